// Round 15
// baseline (379.326 us; speedup 1.0000x reference)
//
#include <hip/hip_runtime.h>
#include <hip/hip_bf16.h>
#include <math.h>

// Problem constants (from reference): H=4 heads, F=64 per-head, H*F=256.
#define HF    256
#define HEADS 4
#define FD    64
#define NEG_SLOPE 0.2f

typedef __attribute__((ext_vector_type(8))) short short8;
typedef __attribute__((ext_vector_type(4))) float f32x4;

__device__ __forceinline__ float wave_sum(float v) {
  #pragma unroll
  for (int off = 32; off; off >>= 1) v += __shfl_xor(v, off);
  return v;
}

// f32 -> bf16 round-to-nearest-even (raw bits).
__device__ __forceinline__ unsigned short f2bf(float f) {
  unsigned u = __float_as_uint(f);
  u += 0x7FFFu + ((u >> 16) & 1u);
  return (unsigned short)(u >> 16);
}
__device__ __forceinline__ float bf2f(unsigned short u) {
  return __uint_as_float((unsigned)u << 16);
}
__device__ __forceinline__ float bf2fs(short s) {
  return __uint_as_float(((unsigned)(unsigned short)s) << 16);
}

// async global->LDS, 16 B per lane (wave-uniform LDS base + lane*16).
__device__ __forceinline__ void gload_lds16(const void* g, void* l) {
  __builtin_amdgcn_global_load_lds((const unsigned int*)g, (unsigned int*)l,
                                   16, 0, 0);
}

// ---------------------------------------------------------------------------
// bf16 MFMA GEMM: C[Mpad x 512] = A[Mpad x K] @ B[K x 512], B given
// pre-transposed as BT[512 x K]. Output cols 0..255 -> featbf, 256..511 ->
// resbf (both bf16). For the feat half, each wave owns exactly one head's 64
// columns -> el/er computed in-register (16-lane shfl reduce over f32 acc).
// 128x128 tile, 4 waves (2x2), 4x4 fragments of 16x16x32, BK=32 (m97-lite).
// ---------------------------------------------------------------------------
template<int K>
__global__ __launch_bounds__(256) void gemm_mfma(
    const unsigned short* __restrict__ A,   // [Mpad][K] bf16 bits
    const unsigned short* __restrict__ BT,  // [512][K]  bf16 bits
    const float* __restrict__ al, const float* __restrict__ ar,
    unsigned short* __restrict__ featbf, unsigned short* __restrict__ resbf,
    float* __restrict__ el, float* __restrict__ er, int M)
{
  __shared__ __align__(16) unsigned short As[128 * 32];
  __shared__ __align__(16) unsigned short Bs[128 * 32];
  const int t    = threadIdx.x;
  const int lane = t & 63, w = t >> 6;
  const int wr = w >> 1, wc = w & 1;
  const int l15 = lane & 15, lhi = lane >> 4;
  const int row0 = blockIdx.x * 128;
  const int n0b  = blockIdx.y;             // 0,1 -> feat; 2,3 -> res

  // staging chunks: 512 chunks of 16B per tile; chunk c: row=c>>2, col8=(c&3)*8
  const int c0 = w * 128 + lane;
  const int c1 = c0 + 64;
  const unsigned short* gA0 = A  + (size_t)(row0 + (c0 >> 2)) * K + (c0 & 3) * 8;
  const unsigned short* gA1 = A  + (size_t)(row0 + (c1 >> 2)) * K + (c1 & 3) * 8;
  const unsigned short* gB0 = BT + (size_t)(n0b * 128 + (c0 >> 2)) * K + (c0 & 3) * 8;
  const unsigned short* gB1 = BT + (size_t)(n0b * 128 + (c1 >> 2)) * K + (c1 & 3) * 8;
  unsigned short* lA0 = &As[w * 1024];
  unsigned short* lA1 = &As[w * 1024 + 512];
  unsigned short* lB0 = &Bs[w * 1024];
  unsigned short* lB1 = &Bs[w * 1024 + 512];

  f32x4 acc[4][4];
  #pragma unroll
  for (int i = 0; i < 4; ++i)
    #pragma unroll
    for (int j = 0; j < 4; ++j)
      acc[i][j] = (f32x4){0.f, 0.f, 0.f, 0.f};

  for (int k0 = 0; k0 < K; k0 += 32) {
    __syncthreads();                       // prev iter's ds_reads done
    gload_lds16(gA0 + k0, lA0);
    gload_lds16(gA1 + k0, lA1);
    gload_lds16(gB0 + k0, lB0);
    gload_lds16(gB1 + k0, lB1);
    __syncthreads();                       // drains vmcnt -> LDS tiles ready

    short8 a[4], b[4];
    #pragma unroll
    for (int im = 0; im < 4; ++im)
      a[im] = *(const short8*)&As[(wr * 64 + im * 16 + l15) * 32 + lhi * 8];
    #pragma unroll
    for (int jn = 0; jn < 4; ++jn)
      b[jn] = *(const short8*)&Bs[(wc * 64 + jn * 16 + l15) * 32 + lhi * 8];
    #pragma unroll
    for (int im = 0; im < 4; ++im)
      #pragma unroll
      for (int jn = 0; jn < 4; ++jn)
        acc[im][jn] = __builtin_amdgcn_mfma_f32_16x16x32_bf16(
            a[im], b[jn], acc[im][jn], 0, 0, 0);
  }

  // C/D layout: col = lane&15, row = (lane>>4)*4 + q   [m89/m91 verified]
  unsigned short* outp = (n0b < 2) ? featbf : resbf;
  const int colbase = (n0b & 1) * 128 + wc * 64;
  #pragma unroll
  for (int im = 0; im < 4; ++im) {
    const int rowb = row0 + wr * 64 + im * 16 + lhi * 4;
    #pragma unroll
    for (int q = 0; q < 4; ++q) {
      if (rowb + q < M) {
        unsigned short* rp = outp + (size_t)(rowb + q) * HF + colbase;
        #pragma unroll
        for (int jn = 0; jn < 4; ++jn)
          rp[jn * 16 + l15] = f2bf(acc[im][jn][q]);
      }
    }
  }

  // el/er for the feat half: wave (n0b,wc) owns head hd's full 64 columns.
  if (n0b < 2) {
    const int hd = n0b * 2 + wc;
    float alv[4], arv[4];
    #pragma unroll
    for (int jn = 0; jn < 4; ++jn) {
      alv[jn] = al[hd * FD + jn * 16 + l15];
      arv[jn] = ar[hd * FD + jn * 16 + l15];
    }
    #pragma unroll
    for (int im = 0; im < 4; ++im) {
      #pragma unroll
      for (int q = 0; q < 4; ++q) {
        float es = 0.f, rs = 0.f;
        #pragma unroll
        for (int jn = 0; jn < 4; ++jn) {
          es = fmaf(acc[im][jn][q], alv[jn], es);
          rs = fmaf(acc[im][jn][q], arv[jn], rs);
        }
        #pragma unroll
        for (int off = 1; off < 16; off <<= 1) {   // reduce across l15 group
          es += __shfl_xor(es, off);
          rs += __shfl_xor(rs, off);
        }
        const int row = row0 + wr * 64 + im * 16 + lhi * 4 + q;
        if (l15 == 0 && row < M) {
          el[row * HEADS + hd] = es;
          er[row * HEADS + hd] = rs;
        }
      }
    }
  }
}

// ---------------------------------------------------------------------------
// Fused conversions + scratch init + graph-offset build (gid is SORTED):
// x->bf16 | BT1 | BT2 | counts=0 | cursor=0 | goffs boundary-fill.
// goffs[g] = first node index with gid >= g; graph g = [goffs[g], goffs[g+1]).
// ---------------------------------------------------------------------------
__global__ void k_cvt_init(
    const float* __restrict__ x,
    const float* __restrict__ W1, const float* __restrict__ Wres1,
    const float* __restrict__ W2, const float* __restrict__ Wres2,
    unsigned short* __restrict__ xbf, unsigned short* __restrict__ BT1,
    unsigned short* __restrict__ BT2, int* __restrict__ counts,
    int* __restrict__ cursor, const int* __restrict__ gid,
    int* __restrict__ goffs, int n4, int N, int G)
{
  int i = blockIdx.x * 256 + threadIdx.x;
  if (i < n4) {
    float4 v = ((const float4*)x)[i];
    ushort4 o;
    o.x = f2bf(v.x); o.y = f2bf(v.y); o.z = f2bf(v.z); o.w = f2bf(v.w);
    ((ushort4*)xbf)[i] = o;
    return;
  }
  i -= n4;
  if (i < 512 * 64) {
    int j = i >> 6, k = i & 63;
    float v = (j < HF) ? W1[k * HF + j] : Wres1[k * HF + (j - HF)];
    BT1[i] = f2bf(v);
    return;
  }
  i -= 512 * 64;
  if (i < 512 * 256) {
    int j = i >> 8, k = i & 255;
    float v = (j < HF) ? W2[k * HF + j] : Wres2[k * HF + (j - HF)];
    BT2[i] = f2bf(v);
    return;
  }
  i -= 512 * 256;
  if (i < N) { counts[i] = 0; return; }
  i -= N;
  if (i < N) { cursor[i] = 0; return; }
  i -= N;
  if (i < N) {
    const int g1 = gid[i];
    if (i == 0) {
      for (int g = 0; g <= g1; ++g) goffs[g] = 0;
    } else {
      const int g0 = gid[i - 1];
      for (int g = g0 + 1; g <= g1; ++g) goffs[g] = i;
    }
    if (i == N - 1) {
      for (int g = g1 + 1; g <= G; ++g) goffs[g] = N;
    }
  }
}

// ---------------------------------------------------------------------------
// CSR build: histogram -> 2-level exclusive scan -> scatter.
// ---------------------------------------------------------------------------
__global__ void k_hist(const int* __restrict__ dst, int* __restrict__ counts, int E) {
  int i = blockIdx.x * 256 + threadIdx.x;
  if (i < E) atomicAdd(&counts[dst[i]], 1);
}

__global__ __launch_bounds__(256) void k_scan1(
    const int* __restrict__ counts, int* __restrict__ offs,
    int* __restrict__ bsum, int n)
{
  __shared__ int lds[256];
  const int b = blockIdx.x, t = threadIdx.x;
  const int base = b * 1024 + t * 4;
  int v[4];
  #pragma unroll
  for (int i = 0; i < 4; ++i) { int idx = base + i; v[i] = (idx < n) ? counts[idx] : 0; }
  int tsum = v[0] + v[1] + v[2] + v[3];
  lds[t] = tsum;
  __syncthreads();
  for (int off = 1; off < 256; off <<= 1) {
    int x = (t >= off) ? lds[t - off] : 0;
    __syncthreads();
    lds[t] += x;
    __syncthreads();
  }
  int run = lds[t] - tsum;
  #pragma unroll
  for (int i = 0; i < 4; ++i) {
    int idx = base + i;
    if (idx < n) offs[idx] = run;
    run += v[i];
  }
  if (t == 255) bsum[b] = lds[255];
}

// Wave-parallel block-sum scan (nb <= 64 on this problem; serial fallback).
__global__ void k_scan2(int* __restrict__ bsum, int nb, int* __restrict__ offs, int n) {
  const int t = threadIdx.x;                  // 64 threads
  if (nb <= 64) {
    int v = (t < nb) ? bsum[t] : 0;
    int inc = v;
    #pragma unroll
    for (int off = 1; off < 64; off <<= 1) {
      int u = __shfl_up(inc, off);
      if (t >= off) inc += u;
    }
    if (t < nb) bsum[t] = inc - v;            // exclusive prefix
    int total = __shfl(inc, 63);
    if (t == 0) offs[n] = total;              // == E
  } else if (t == 0) {
    int run = 0;
    for (int b = 0; b < nb; ++b) { int x = bsum[b]; bsum[b] = run; run += x; }
    offs[n] = run;
  }
}

__global__ void k_scan3(int* __restrict__ offs, const int* __restrict__ bsum, int n) {
  int i = blockIdx.x * 256 + threadIdx.x;
  if (i < n) offs[i] += bsum[i >> 10];
}

__global__ void k_scatter(const int* __restrict__ src, const int* __restrict__ dst,
                          const int* __restrict__ offs, int* __restrict__ cursor,
                          int* __restrict__ csr_src, int E) {
  int i = blockIdx.x * 256 + threadIdx.x;
  if (i < E) {
    int d = dst[i];
    int pos = offs[d] + atomicAdd(&cursor[d], 1);
    csr_src[pos] = src[i];
  }
}

// ---------------------------------------------------------------------------
// GAT aggregation core, 16B-gather layout.
//   Pass 1 (h = t&3, j = t>>2 stride 64): w = exp(leaky(el+er)) -> sw4[j][h],
//     per-head denom partials -> sden[w][h]. No max-subtraction (scores O(+-3),
//     exp f32-safe, softmax ratio identical).
//   Pass 2 (eh = lane>>5 edge-of-pair, c = lane&31 chunk, head = c>>3): each
//     half-wave walks edges j = 2w+eh (mod 8); lane loads short8 = 16B (8
//     feats) -> ONE wave-load covers TWO rows (halves load issues + LDS
//     broadcasts + addressing vs the 8B layout). 2-way unroll.
//   Reduce: saccA/B[w][lane]; epilogue lane<32 owns chunk c: sums 4 waves x
//     2 halves, /denom, +res, +bias, ELU.
// ---------------------------------------------------------------------------
#define DCAP 128

#define EDGE_BODY(J)                                                      \
  {                                                                       \
    const int   s_ = ssrc[(J)];                                           \
    const float w_ = sw4[(J) * 4 + hd2];                                  \
    const short8 f8 = *((const short8*)(feat + (size_t)s_ * HF) + c);     \
    accA.x = fmaf(w_, bf2fs(f8[0]), accA.x);                              \
    accA.y = fmaf(w_, bf2fs(f8[1]), accA.y);                              \
    accA.z = fmaf(w_, bf2fs(f8[2]), accA.z);                              \
    accA.w = fmaf(w_, bf2fs(f8[3]), accA.w);                              \
    accB.x = fmaf(w_, bf2fs(f8[4]), accB.x);                              \
    accB.y = fmaf(w_, bf2fs(f8[5]), accB.y);                              \
    accB.z = fmaf(w_, bf2fs(f8[6]), accB.z);                              \
    accB.w = fmaf(w_, bf2fs(f8[7]), accB.w);                              \
  }

#define FEDGE_BODY(J)                                                     \
  {                                                                       \
    const int s_ = csr_src[s0 + (J)];                                     \
    float sc_ = el[s_ * HEADS + hd2] + ernd;                              \
    sc_ = sc_ > 0.f ? sc_ : NEG_SLOPE * sc_;                              \
    const float w_ = __expf(sc_);                                         \
    dpu += w_;                                                            \
    const short8 f8 = *((const short8*)(feat + (size_t)s_ * HF) + c);     \
    accA.x = fmaf(w_, bf2fs(f8[0]), accA.x);                              \
    accA.y = fmaf(w_, bf2fs(f8[1]), accA.y);                              \
    accA.z = fmaf(w_, bf2fs(f8[2]), accA.z);                              \
    accA.w = fmaf(w_, bf2fs(f8[3]), accA.w);                              \
    accB.x = fmaf(w_, bf2fs(f8[4]), accB.x);                              \
    accB.y = fmaf(w_, bf2fs(f8[5]), accB.y);                              \
    accB.z = fmaf(w_, bf2fs(f8[6]), accB.z);                              \
    accB.w = fmaf(w_, bf2fs(f8[7]), accB.w);                              \
  }

__global__ __launch_bounds__(256) void agg_l1(
    const unsigned short* __restrict__ feat, const unsigned short* __restrict__ res,
    const float* __restrict__ el, const float* __restrict__ er,
    const float* __restrict__ bias, const int* __restrict__ csr_src,
    const int* __restrict__ offs, unsigned short* __restrict__ outbf)
{
  __shared__ int    ssrc[DCAP];
  __shared__ float  sw4[DCAP * 4];          // [j][h]
  __shared__ float  sden[4][4];             // [wave][h]
  __shared__ float4 saccA[4][64];
  __shared__ float4 saccB[4][64];
  const int n = blockIdx.x;
  const int t = threadIdx.x;
  const int lane = t & 63, w = t >> 6;
  const int h = t & 3, j0 = t >> 2;         // pass-1 layout
  const int eh = lane >> 5;                 // pass-2: which edge of the pair
  const int c  = lane & 31;                 // pass-2: 16B chunk within row
  const int hd2 = c >> 3;                   // pass-2: head of this chunk
  const int s0  = offs[n];
  const int deg = offs[n + 1] - s0;         // >= 1 (self-loops)
  const bool cached = (deg <= DCAP);

  // ---- pass 1: exp-scores into LDS + per-head denom partials ----
  if (cached) {
    const float ernh = er[n * HEADS + h];
    float dp = 0.f;
    for (int j = j0; j < deg; j += 64) {
      int s = csr_src[s0 + j];
      float sc = el[s * HEADS + h] + ernh;
      sc = sc > 0.f ? sc : NEG_SLOPE * sc;  // leaky_relu
      float wv = __expf(sc);
      sw4[j * 4 + h] = wv;
      if (h == 0) ssrc[j] = s;
      dp += wv;
    }
    #pragma unroll
    for (int off = 4; off < 64; off <<= 1) dp += __shfl_xor(dp, off);
    if (lane < 4) sden[w][lane] = dp;
  }
  __syncthreads();

  // ---- pass 2: half-wave per edge, 16B/lane ----
  float4 accA = make_float4(0.f, 0.f, 0.f, 0.f);
  float4 accB = make_float4(0.f, 0.f, 0.f, 0.f);
  if (cached) {
    int j = 2 * w + eh;
    for (; j + 8 < deg; j += 16) { EDGE_BODY(j) EDGE_BODY(j + 8) }
    if (j < deg) EDGE_BODY(j)
  } else {                                  // rare deg>128 fallback
    const float ernd = er[n * HEADS + hd2];
    float dpu = 0.f;
    for (int j = 2 * w + eh; j < deg; j += 8) FEDGE_BODY(j)
    dpu += __shfl_xor(dpu, 32);             // combine the two halves
    if (eh == 0 && (c & 7) == 0) sden[w][hd2] = dpu;
  }
  saccA[w][lane] = accA;
  saccB[w][lane] = accB;
  __syncthreads();

  // ---- epilogue: wave 0, lane<32 owns chunk `lane` ----
  if (w == 0 && lane < 32) {
    float A0 = 0.f, A1 = 0.f, A2 = 0.f, A3 = 0.f;
    float B0 = 0.f, B1 = 0.f, B2 = 0.f, B3 = 0.f;
    #pragma unroll
    for (int ww = 0; ww < 4; ++ww) {
      float4 a0 = saccA[ww][lane], a1 = saccA[ww][lane + 32];
      float4 b0 = saccB[ww][lane], b1 = saccB[ww][lane + 32];
      A0 += a0.x + a1.x; A1 += a0.y + a1.y;
      A2 += a0.z + a1.z; A3 += a0.w + a1.w;
      B0 += b0.x + b1.x; B1 += b0.y + b1.y;
      B2 += b0.z + b1.z; B3 += b0.w + b1.w;
    }
    const float denom = sden[0][hd2] + sden[1][hd2] +
                        sden[2][hd2] + sden[3][hd2];
    const float rden = 1.f / denom;
    const short8 rv = *((const short8*)&res[(size_t)n * HF] + lane);
    const float4 bv0 = ((const float4*)bias)[2 * lane];
    const float4 bv1 = ((const float4*)bias)[2 * lane + 1];
    float v0 = A0 * rden + bf2fs(rv[0]) + bv0.x;
    float v1 = A1 * rden + bf2fs(rv[1]) + bv0.y;
    float v2 = A2 * rden + bf2fs(rv[2]) + bv0.z;
    float v3 = A3 * rden + bf2fs(rv[3]) + bv0.w;
    float v4 = B0 * rden + bf2fs(rv[4]) + bv1.x;
    float v5 = B1 * rden + bf2fs(rv[5]) + bv1.y;
    float v6 = B2 * rden + bf2fs(rv[6]) + bv1.z;
    float v7 = B3 * rden + bf2fs(rv[7]) + bv1.w;
    v0 = v0 > 0.f ? v0 : expm1f(v0);        // ELU(alpha=1)
    v1 = v1 > 0.f ? v1 : expm1f(v1);
    v2 = v2 > 0.f ? v2 : expm1f(v2);
    v3 = v3 > 0.f ? v3 : expm1f(v3);
    v4 = v4 > 0.f ? v4 : expm1f(v4);
    v5 = v5 > 0.f ? v5 : expm1f(v5);
    v6 = v6 > 0.f ? v6 : expm1f(v6);
    v7 = v7 > 0.f ? v7 : expm1f(v7);
    short8 o;
    o[0] = (short)f2bf(v0); o[1] = (short)f2bf(v1);
    o[2] = (short)f2bf(v2); o[3] = (short)f2bf(v3);
    o[4] = (short)f2bf(v4); o[5] = (short)f2bf(v5);
    o[6] = (short)f2bf(v6); o[7] = (short)f2bf(v7);
    *((short8*)&outbf[(size_t)n * HF] + lane) = o;
  }
}

// ---------------------------------------------------------------------------
// Layer 2: same core; epilogue head-means via shfl_xor(8,16) then writes the
// f32 h2 row + node_w[n] = sigmoid(dot(row, Ww)+bw). No atomics (gid sorted;
// per-graph reduction in k_rp).
// ---------------------------------------------------------------------------
__global__ __launch_bounds__(256) void agg_l2(
    const unsigned short* __restrict__ feat, const unsigned short* __restrict__ res,
    const float* __restrict__ el, const float* __restrict__ er,
    const float* __restrict__ bias, const int* __restrict__ csr_src,
    const int* __restrict__ offs, const float* __restrict__ Ww,
    const float* __restrict__ bw, float* __restrict__ h2out,
    float* __restrict__ node_w)
{
  __shared__ int    ssrc[DCAP];
  __shared__ float  sw4[DCAP * 4];
  __shared__ float  sden[4][4];
  __shared__ float4 saccA[4][64];
  __shared__ float4 saccB[4][64];
  const int n = blockIdx.x;
  const int t = threadIdx.x;
  const int lane = t & 63, w = t >> 6;
  const int h = t & 3, j0 = t >> 2;
  const int eh = lane >> 5;
  const int c  = lane & 31;
  const int hd2 = c >> 3;
  const int s0  = offs[n];
  const int deg = offs[n + 1] - s0;
  const bool cached = (deg <= DCAP);

  if (cached) {
    const float ernh = er[n * HEADS + h];
    float dp = 0.f;
    for (int j = j0; j < deg; j += 64) {
      int s = csr_src[s0 + j];
      float sc = el[s * HEADS + h] + ernh;
      sc = sc > 0.f ? sc : NEG_SLOPE * sc;
      float wv = __expf(sc);
      sw4[j * 4 + h] = wv;
      if (h == 0) ssrc[j] = s;
      dp += wv;
    }
    #pragma unroll
    for (int off = 4; off < 64; off <<= 1) dp += __shfl_xor(dp, off);
    if (lane < 4) sden[w][lane] = dp;
  }
  __syncthreads();

  float4 accA = make_float4(0.f, 0.f, 0.f, 0.f);
  float4 accB = make_float4(0.f, 0.f, 0.f, 0.f);
  if (cached) {
    int j = 2 * w + eh;
    for (; j + 8 < deg; j += 16) { EDGE_BODY(j) EDGE_BODY(j + 8) }
    if (j < deg) EDGE_BODY(j)
  } else {
    const float ernd = er[n * HEADS + hd2];
    float dpu = 0.f;
    for (int j = 2 * w + eh; j < deg; j += 8) FEDGE_BODY(j)
    dpu += __shfl_xor(dpu, 32);
    if (eh == 0 && (c & 7) == 0) sden[w][hd2] = dpu;
  }
  saccA[w][lane] = accA;
  saccB[w][lane] = accB;
  __syncthreads();

  // ---- epilogue: all 64 lanes of wave 0 compute (lanes >=32 duplicate
  // lanes <32 so the head-mean shuffles have valid sources); stores gated.
  if (w == 0) {
    const int l = lane & 31;
    const int hdl = l >> 3;
    float A0 = 0.f, A1 = 0.f, A2 = 0.f, A3 = 0.f;
    float B0 = 0.f, B1 = 0.f, B2 = 0.f, B3 = 0.f;
    #pragma unroll
    for (int ww = 0; ww < 4; ++ww) {
      float4 a0 = saccA[ww][l], a1 = saccA[ww][l + 32];
      float4 b0 = saccB[ww][l], b1 = saccB[ww][l + 32];
      A0 += a0.x + a1.x; A1 += a0.y + a1.y;
      A2 += a0.z + a1.z; A3 += a0.w + a1.w;
      B0 += b0.x + b1.x; B1 += b0.y + b1.y;
      B2 += b0.z + b1.z; B3 += b0.w + b1.w;
    }
    const float denom = sden[0][hdl] + sden[1][hdl] +
                        sden[2][hdl] + sden[3][hdl];
    const float rden = 1.f / denom;
    const short8 rv = *((const short8*)&res[(size_t)n * HF] + l);
    const float4 bv0 = ((const float4*)bias)[2 * l];
    const float4 bv1 = ((const float4*)bias)[2 * l + 1];
    float v0 = A0 * rden + bf2fs(rv[0]) + bv0.x;
    float v1 = A1 * rden + bf2fs(rv[1]) + bv0.y;
    float v2 = A2 * rden + bf2fs(rv[2]) + bv0.z;
    float v3 = A3 * rden + bf2fs(rv[3]) + bv0.w;
    float v4 = B0 * rden + bf2fs(rv[4]) + bv1.x;
    float v5 = B1 * rden + bf2fs(rv[5]) + bv1.y;
    float v6 = B2 * rden + bf2fs(rv[6]) + bv1.z;
    float v7 = B3 * rden + bf2fs(rv[7]) + bv1.w;
    v0 = v0 > 0.f ? v0 : expm1f(v0);        // ELU(alpha=1)
    v1 = v1 > 0.f ? v1 : expm1f(v1);
    v2 = v2 > 0.f ? v2 : expm1f(v2);
    v3 = v3 > 0.f ? v3 : expm1f(v3);
    v4 = v4 > 0.f ? v4 : expm1f(v4);
    v5 = v5 > 0.f ? v5 : expm1f(v5);
    v6 = v6 > 0.f ? v6 : expm1f(v6);
    v7 = v7 > 0.f ? v7 : expm1f(v7);
    // head-mean: chunks {l&7, +8, +16, +24} are the 4 heads at the same
    // within-head offset.
    #pragma unroll
    for (int off = 8; off <= 16; off <<= 1) {
      v0 += __shfl_xor(v0, off); v1 += __shfl_xor(v1, off);
      v2 += __shfl_xor(v2, off); v3 += __shfl_xor(v3, off);
      v4 += __shfl_xor(v4, off); v5 += __shfl_xor(v5, off);
      v6 += __shfl_xor(v6, off); v7 += __shfl_xor(v7, off);
    }
    const float m0 = 0.25f * v0, m1 = 0.25f * v1, m2 = 0.25f * v2,
                m3 = 0.25f * v3, m4 = 0.25f * v4, m5 = 0.25f * v5,
                m6 = 0.25f * v6, m7 = 0.25f * v7;
    if (lane < 8) {
      ((float4*)&h2out[(size_t)n * FD])[2 * lane]     = make_float4(m0, m1, m2, m3);
      ((float4*)&h2out[(size_t)n * FD])[2 * lane + 1] = make_float4(m4, m5, m6, m7);
    }
    const float4 w0 = ((const float4*)Ww)[2 * (l & 7)];
    const float4 w1 = ((const float4*)Ww)[2 * (l & 7) + 1];
    float part = m0 * w0.x + m1 * w0.y + m2 * w0.z + m3 * w0.w +
                 m4 * w1.x + m5 * w1.y + m6 * w1.z + m7 * w1.w;
    part += __shfl_xor(part, 1);
    part += __shfl_xor(part, 2);
    part += __shfl_xor(part, 4);
    if (lane == 0)
      node_w[n] = 1.f / (1.f + __expf(-(part + bw[0])));
  }
}

// ---------------------------------------------------------------------------
// Fused per-graph readout + predictor: one WAVE per graph (gid sorted ->
// contiguous node range via goffs, zero atomics). Lane f streams wsum/hmax;
// gfeat staged in LDS; lanes 0-31 compute the 32 hidden units; shfl-reduce
// the final dot. Empty graphs: ws=0, mx=-inf (JAX segment semantics).
// ---------------------------------------------------------------------------
__global__ __launch_bounds__(256) void k_rp(
    const float* __restrict__ h2, const float* __restrict__ node_w,
    const int* __restrict__ goffs,
    const float* __restrict__ Wp1, const float* __restrict__ bp1,
    const float* __restrict__ Wp2, const float* __restrict__ bp2,
    float* __restrict__ out, int G)
{
  __shared__ float lws[4][FD];
  __shared__ float lmx[4][FD];
  const int w = threadIdx.x >> 6, lane = threadIdx.x & 63;
  const int g = blockIdx.x * 4 + w;

  float ws = 0.f, mx = -INFINITY;
  if (g < G) {
    const int n0 = goffs[g], n1 = goffs[g + 1];
    for (int n = n0; n < n1; ++n) {
      float v  = h2[(size_t)n * FD + lane];
      float wn = node_w[n];
      ws = fmaf(wn, v, ws);
      mx = fmaxf(mx, v);
    }
  }
  lws[w][lane] = ws;
  lmx[w][lane] = mx;
  __syncthreads();

  float acc = 0.f;
  if (g < G && lane < 32) {
    acc = bp1[lane];
    #pragma unroll 4
    for (int k = 0; k < FD; ++k)
      acc = fmaf(lws[w][k], Wp1[k * 32 + lane], acc);
    #pragma unroll 4
    for (int k = 0; k < FD; ++k)
      acc = fmaf(lmx[w][k], Wp1[(FD + k) * 32 + lane], acc);
    acc = fmaxf(acc, 0.f) * Wp2[lane];
  }
  #pragma unroll
  for (int off = 1; off < 32; off <<= 1)    // reduce lanes 0-31
    acc += __shfl_xor(acc, off);
  if (g < G && lane == 0) out[g] = acc + bp2[0];
}

// ---------------------------------------------------------------------------
extern "C" void kernel_launch(void* const* d_in, const int* in_sizes, int n_in,
                              void* d_out, int out_size, void* d_ws, size_t ws_size,
                              hipStream_t stream) {
  const float* x     = (const float*)d_in[0];
  const int*   src   = (const int*)  d_in[1];
  const int*   dst   = (const int*)  d_in[2];
  const int*   gid   = (const int*)  d_in[3];
  const float* W1    = (const float*)d_in[4];
  const float* al1   = (const float*)d_in[5];
  const float* ar1   = (const float*)d_in[6];
  const float* b1    = (const float*)d_in[7];
  const float* Wres1 = (const float*)d_in[8];
  const float* W2    = (const float*)d_in[9];
  const float* al2   = (const float*)d_in[10];
  const float* ar2   = (const float*)d_in[11];
  const float* b2    = (const float*)d_in[12];
  const float* Wres2 = (const float*)d_in[13];
  const float* Ww    = (const float*)d_in[14];
  const float* bw    = (const float*)d_in[15];
  const float* Wp1   = (const float*)d_in[16];
  const float* bp1   = (const float*)d_in[17];
  const float* Wp2   = (const float*)d_in[18];
  const float* bp2   = (const float*)d_in[19];
  float* out = (float*)d_out;

  const int N = in_sizes[3];        // gid has N elements
  const int E = in_sizes[1];        // src has E elements
  const int G = out_size;           // output is [G,1]
  const int Mpad = (N + 127) & ~127;

  // ---- workspace carve (256B-aligned) ----
  char* p = (char*)d_ws;
  auto alloc = [&](size_t bytes) {
    char* r = p;
    p += (bytes + 255) & ~(size_t)255;
    return r;
  };
  unsigned short* featbf  = (unsigned short*)alloc((size_t)Mpad * HF * 2);
  unsigned short* resbf   = (unsigned short*)alloc((size_t)Mpad * HF * 2);
  float*          el      = (float*)         alloc((size_t)N * HEADS * 4);
  float*          er      = (float*)         alloc((size_t)N * HEADS * 4);
  int*            counts  = (int*)           alloc((size_t)N * 4);
  int*            cursor  = (int*)           alloc((size_t)N * 4);
  int*            offs    = (int*)           alloc((size_t)(N + 1) * 4);
  const int nb            = (N + 1023) / 1024;
  int*            bsum    = (int*)           alloc((size_t)nb * 4);
  int*            csr_src = (int*)           alloc((size_t)E * 4);
  float*          h2      = (float*)         alloc((size_t)N * FD * 4);
  float*          node_w  = (float*)         alloc((size_t)N * 4);
  int*            goffs   = (int*)           alloc((size_t)(G + 1) * 4);
  unsigned short* xbf     = (unsigned short*)alloc((size_t)Mpad * 64 * 2);
  unsigned short* h1bf    = (unsigned short*)alloc((size_t)Mpad * HF * 2);
  unsigned short* BT1     = (unsigned short*)alloc((size_t)512 * 64 * 2);
  unsigned short* BT2     = (unsigned short*)alloc((size_t)512 * 256 * 2);
  (void)ws_size; (void)n_in;

  // ---- conversions + scratch init + goffs build (one kernel) ----
  const int n4 = N * 64 / 4;
  const int init_total = n4 + 512 * 64 + 512 * 256 + N + N + N;
  k_cvt_init<<<(init_total + 255) / 256, 256, 0, stream>>>(
      x, W1, Wres1, W2, Wres2, xbf, BT1, BT2,
      counts, cursor, gid, goffs, n4, N, G);

  // ---- CSR by destination (shared by both layers) ----
  k_hist   <<<(E + 255) / 256, 256, 0, stream>>>(dst, counts, E);
  k_scan1  <<<nb, 256, 0, stream>>>(counts, offs, bsum, N);
  k_scan2  <<<1, 64, 0, stream>>>(bsum, nb, offs, N);
  k_scan3  <<<(N + 255) / 256, 256, 0, stream>>>(offs, bsum, N);
  k_scatter<<<(E + 255) / 256, 256, 0, stream>>>(src, dst, offs, cursor, csr_src, E);

  dim3 gg(Mpad / 128, 4);

  // ---- layer 1 (flatten) ----
  gemm_mfma<64> <<<gg, 256, 0, stream>>>(xbf, BT1, al1, ar1,
                                         featbf, resbf, el, er, N);
  agg_l1        <<<N, 256, 0, stream>>>(featbf, resbf, el, er, b1, csr_src,
                                        offs, h1bf);

  // ---- layer 2 (mean) ----
  gemm_mfma<256><<<gg, 256, 0, stream>>>(h1bf, BT2, al2, ar2,
                                         featbf, resbf, el, er, N);
  agg_l2        <<<N, 256, 0, stream>>>(featbf, resbf, el, er, b2, csr_src,
                                        offs, Ww, bw, h2, node_w);

  // ---- fused per-graph readout + predictor (no atomics) ----
  k_rp<<<(G + 3) / 4, 256, 0, stream>>>(h2, node_w, goffs,
                                        Wp1, bp1, Wp2, bp2, out, G);
}

// Round 16
// 354.345 us; speedup vs baseline: 1.0705x; 1.0705x over previous
//
#include <hip/hip_runtime.h>
#include <hip/hip_bf16.h>
#include <math.h>

// Problem constants (from reference): H=4 heads, F=64 per-head, H*F=256.
#define HF    256
#define HEADS 4
#define FD    64
#define NEG_SLOPE 0.2f

typedef __attribute__((ext_vector_type(8))) short short8;
typedef __attribute__((ext_vector_type(4))) float f32x4;

__device__ __forceinline__ float wave_sum(float v) {
  #pragma unroll
  for (int off = 32; off; off >>= 1) v += __shfl_xor(v, off);
  return v;
}

// f32 -> bf16 round-to-nearest-even (raw bits).
__device__ __forceinline__ unsigned short f2bf(float f) {
  unsigned u = __float_as_uint(f);
  u += 0x7FFFu + ((u >> 16) & 1u);
  return (unsigned short)(u >> 16);
}
__device__ __forceinline__ float bf2f(unsigned short u) {
  return __uint_as_float((unsigned)u << 16);
}

// async global->LDS, 16 B per lane (wave-uniform LDS base + lane*16).
__device__ __forceinline__ void gload_lds16(const void* g, void* l) {
  __builtin_amdgcn_global_load_lds((const unsigned int*)g, (unsigned int*)l,
                                   16, 0, 0);
}

// ---------------------------------------------------------------------------
// bf16 MFMA GEMM: C[Mpad x 512] = A[Mpad x K] @ B[K x 512], B given
// pre-transposed as BT[512 x K]. Output cols 0..255 -> featbf, 256..511 ->
// resbf (both bf16). For the feat half, each wave owns exactly one head's 64
// columns -> el/er computed in-register (16-lane shfl reduce over f32 acc).
// 128x128 tile, 4 waves (2x2), 4x4 fragments of 16x16x32, BK=32 (m97-lite).
// GRID SWIZZLE (round 16): n0b = blockIdx.x (4, fastest-varying), row-tile =
// blockIdx.y -> the 4 column-blocks sharing one A-tile dispatch adjacently,
// so A-tile reads 2-4 hit L2 instead of round-tripping to L3.
// ---------------------------------------------------------------------------
template<int K>
__global__ __launch_bounds__(256) void gemm_mfma(
    const unsigned short* __restrict__ A,   // [Mpad][K] bf16 bits
    const unsigned short* __restrict__ BT,  // [512][K]  bf16 bits
    const float* __restrict__ al, const float* __restrict__ ar,
    unsigned short* __restrict__ featbf, unsigned short* __restrict__ resbf,
    float* __restrict__ el, float* __restrict__ er, int M)
{
  __shared__ __align__(16) unsigned short As[128 * 32];
  __shared__ __align__(16) unsigned short Bs[128 * 32];
  const int t    = threadIdx.x;
  const int lane = t & 63, w = t >> 6;
  const int wr = w >> 1, wc = w & 1;
  const int l15 = lane & 15, lhi = lane >> 4;
  const int row0 = blockIdx.y * 128;       // row-tile (slow-varying)
  const int n0b  = blockIdx.x;             // 0,1 -> feat; 2,3 -> res (fast)

  // staging chunks: 512 chunks of 16B per tile; chunk c: row=c>>2, col8=(c&3)*8
  const int c0 = w * 128 + lane;
  const int c1 = c0 + 64;
  const unsigned short* gA0 = A  + (size_t)(row0 + (c0 >> 2)) * K + (c0 & 3) * 8;
  const unsigned short* gA1 = A  + (size_t)(row0 + (c1 >> 2)) * K + (c1 & 3) * 8;
  const unsigned short* gB0 = BT + (size_t)(n0b * 128 + (c0 >> 2)) * K + (c0 & 3) * 8;
  const unsigned short* gB1 = BT + (size_t)(n0b * 128 + (c1 >> 2)) * K + (c1 & 3) * 8;
  unsigned short* lA0 = &As[w * 1024];
  unsigned short* lA1 = &As[w * 1024 + 512];
  unsigned short* lB0 = &Bs[w * 1024];
  unsigned short* lB1 = &Bs[w * 1024 + 512];

  f32x4 acc[4][4];
  #pragma unroll
  for (int i = 0; i < 4; ++i)
    #pragma unroll
    for (int j = 0; j < 4; ++j)
      acc[i][j] = (f32x4){0.f, 0.f, 0.f, 0.f};

  for (int k0 = 0; k0 < K; k0 += 32) {
    __syncthreads();                       // prev iter's ds_reads done
    gload_lds16(gA0 + k0, lA0);
    gload_lds16(gA1 + k0, lA1);
    gload_lds16(gB0 + k0, lB0);
    gload_lds16(gB1 + k0, lB1);
    __syncthreads();                       // drains vmcnt -> LDS tiles ready

    short8 a[4], b[4];
    #pragma unroll
    for (int im = 0; im < 4; ++im)
      a[im] = *(const short8*)&As[(wr * 64 + im * 16 + l15) * 32 + lhi * 8];
    #pragma unroll
    for (int jn = 0; jn < 4; ++jn)
      b[jn] = *(const short8*)&Bs[(wc * 64 + jn * 16 + l15) * 32 + lhi * 8];
    #pragma unroll
    for (int im = 0; im < 4; ++im)
      #pragma unroll
      for (int jn = 0; jn < 4; ++jn)
        acc[im][jn] = __builtin_amdgcn_mfma_f32_16x16x32_bf16(
            a[im], b[jn], acc[im][jn], 0, 0, 0);
  }

  // C/D layout: col = lane&15, row = (lane>>4)*4 + q   [m89/m91 verified]
  unsigned short* outp = (n0b < 2) ? featbf : resbf;
  const int colbase = (n0b & 1) * 128 + wc * 64;
  #pragma unroll
  for (int im = 0; im < 4; ++im) {
    const int rowb = row0 + wr * 64 + im * 16 + lhi * 4;
    #pragma unroll
    for (int q = 0; q < 4; ++q) {
      if (rowb + q < M) {
        unsigned short* rp = outp + (size_t)(rowb + q) * HF + colbase;
        #pragma unroll
        for (int jn = 0; jn < 4; ++jn)
          rp[jn * 16 + l15] = f2bf(acc[im][jn][q]);
      }
    }
  }

  // el/er for the feat half: wave (n0b,wc) owns head hd's full 64 columns.
  if (n0b < 2) {
    const int hd = n0b * 2 + wc;
    float alv[4], arv[4];
    #pragma unroll
    for (int jn = 0; jn < 4; ++jn) {
      alv[jn] = al[hd * FD + jn * 16 + l15];
      arv[jn] = ar[hd * FD + jn * 16 + l15];
    }
    #pragma unroll
    for (int im = 0; im < 4; ++im) {
      #pragma unroll
      for (int q = 0; q < 4; ++q) {
        float es = 0.f, rs = 0.f;
        #pragma unroll
        for (int jn = 0; jn < 4; ++jn) {
          es = fmaf(acc[im][jn][q], alv[jn], es);
          rs = fmaf(acc[im][jn][q], arv[jn], rs);
        }
        #pragma unroll
        for (int off = 1; off < 16; off <<= 1) {   // reduce across l15 group
          es += __shfl_xor(es, off);
          rs += __shfl_xor(rs, off);
        }
        const int row = row0 + wr * 64 + im * 16 + lhi * 4 + q;
        if (l15 == 0 && row < M) {
          el[row * HEADS + hd] = es;
          er[row * HEADS + hd] = rs;
        }
      }
    }
  }
}

// ---------------------------------------------------------------------------
// Fused conversions + scratch init + graph-offset build (gid is SORTED):
// x->bf16 | BT1 | BT2 | counts=0 | cursor=0 | goffs boundary-fill.
// goffs[g] = first node index with gid >= g; graph g = [goffs[g], goffs[g+1]).
// ---------------------------------------------------------------------------
__global__ void k_cvt_init(
    const float* __restrict__ x,
    const float* __restrict__ W1, const float* __restrict__ Wres1,
    const float* __restrict__ W2, const float* __restrict__ Wres2,
    unsigned short* __restrict__ xbf, unsigned short* __restrict__ BT1,
    unsigned short* __restrict__ BT2, int* __restrict__ counts,
    int* __restrict__ cursor, const int* __restrict__ gid,
    int* __restrict__ goffs, int n4, int N, int G)
{
  int i = blockIdx.x * 256 + threadIdx.x;
  if (i < n4) {
    float4 v = ((const float4*)x)[i];
    ushort4 o;
    o.x = f2bf(v.x); o.y = f2bf(v.y); o.z = f2bf(v.z); o.w = f2bf(v.w);
    ((ushort4*)xbf)[i] = o;
    return;
  }
  i -= n4;
  if (i < 512 * 64) {
    int j = i >> 6, k = i & 63;
    float v = (j < HF) ? W1[k * HF + j] : Wres1[k * HF + (j - HF)];
    BT1[i] = f2bf(v);
    return;
  }
  i -= 512 * 64;
  if (i < 512 * 256) {
    int j = i >> 8, k = i & 255;
    float v = (j < HF) ? W2[k * HF + j] : Wres2[k * HF + (j - HF)];
    BT2[i] = f2bf(v);
    return;
  }
  i -= 512 * 256;
  if (i < N) { counts[i] = 0; return; }
  i -= N;
  if (i < N) { cursor[i] = 0; return; }
  i -= N;
  if (i < N) {
    const int g1 = gid[i];
    if (i == 0) {
      for (int g = 0; g <= g1; ++g) goffs[g] = 0;
    } else {
      const int g0 = gid[i - 1];
      for (int g = g0 + 1; g <= g1; ++g) goffs[g] = i;
    }
    if (i == N - 1) {
      for (int g = g1 + 1; g <= G; ++g) goffs[g] = N;
    }
  }
}

// ---------------------------------------------------------------------------
// CSR build: histogram -> 2-level exclusive scan -> scatter.
// ---------------------------------------------------------------------------
__global__ void k_hist(const int* __restrict__ dst, int* __restrict__ counts, int E) {
  int i = blockIdx.x * 256 + threadIdx.x;
  if (i < E) atomicAdd(&counts[dst[i]], 1);
}

__global__ __launch_bounds__(256) void k_scan1(
    const int* __restrict__ counts, int* __restrict__ offs,
    int* __restrict__ bsum, int n)
{
  __shared__ int lds[256];
  const int b = blockIdx.x, t = threadIdx.x;
  const int base = b * 1024 + t * 4;
  int v[4];
  #pragma unroll
  for (int i = 0; i < 4; ++i) { int idx = base + i; v[i] = (idx < n) ? counts[idx] : 0; }
  int tsum = v[0] + v[1] + v[2] + v[3];
  lds[t] = tsum;
  __syncthreads();
  for (int off = 1; off < 256; off <<= 1) {
    int x = (t >= off) ? lds[t - off] : 0;
    __syncthreads();
    lds[t] += x;
    __syncthreads();
  }
  int run = lds[t] - tsum;
  #pragma unroll
  for (int i = 0; i < 4; ++i) {
    int idx = base + i;
    if (idx < n) offs[idx] = run;
    run += v[i];
  }
  if (t == 255) bsum[b] = lds[255];
}

// Wave-parallel block-sum scan (nb <= 64 on this problem; serial fallback).
__global__ void k_scan2(int* __restrict__ bsum, int nb, int* __restrict__ offs, int n) {
  const int t = threadIdx.x;                  // 64 threads
  if (nb <= 64) {
    int v = (t < nb) ? bsum[t] : 0;
    int inc = v;
    #pragma unroll
    for (int off = 1; off < 64; off <<= 1) {
      int u = __shfl_up(inc, off);
      if (t >= off) inc += u;
    }
    if (t < nb) bsum[t] = inc - v;            // exclusive prefix
    int total = __shfl(inc, 63);
    if (t == 0) offs[n] = total;              // == E
  } else if (t == 0) {
    int run = 0;
    for (int b = 0; b < nb; ++b) { int x = bsum[b]; bsum[b] = run; run += x; }
    offs[n] = run;
  }
}

__global__ void k_scan3(int* __restrict__ offs, const int* __restrict__ bsum, int n) {
  int i = blockIdx.x * 256 + threadIdx.x;
  if (i < n) offs[i] += bsum[i >> 10];
}

__global__ void k_scatter(const int* __restrict__ src, const int* __restrict__ dst,
                          const int* __restrict__ offs, int* __restrict__ cursor,
                          int* __restrict__ csr_src, int E) {
  int i = blockIdx.x * 256 + threadIdx.x;
  if (i < E) {
    int d = dst[i];
    int pos = offs[d] + atomicAdd(&cursor[d], 1);
    csr_src[pos] = src[i];
  }
}

// ---------------------------------------------------------------------------
// GAT aggregation layer 1 (round-14 measured-best structure, reverted from
// the 16B-gather experiment: that one kept VALUBusy at 62% but dropped
// occupancy 74->56% (VGPR 16->40, LDS +4KB) and regressed 90->112 us).
//   Pass 1 (h = t&3, j = t>>2 stride 64): w = exp(leaky(el+er)) -> sw4[j][h],
//     per-head denom partials -> sden[w][h]. No max-subtraction (scores
//     O(+-3), exp f32-safe, softmax ratio identical).
//   Pass 2: wave w walks edges j == w (mod 4); lane loads ushort4 (its 4
//     features of the 512 B row, head = lane>>4); weight = LDS broadcast.
//   Epilogue (wave 0): /denom, +res, +bias, ELU -> bf16 h1 row.
// ---------------------------------------------------------------------------
#define DCAP 128
__global__ __launch_bounds__(256) void agg_l1(
    const unsigned short* __restrict__ feat, const unsigned short* __restrict__ res,
    const float* __restrict__ el, const float* __restrict__ er,
    const float* __restrict__ bias, const int* __restrict__ csr_src,
    const int* __restrict__ offs, unsigned short* __restrict__ outbf)
{
  __shared__ int    ssrc[DCAP];
  __shared__ float  sw4[DCAP * 4];          // [j][h]
  __shared__ float  sden[4][4];             // [wave][h]
  __shared__ float4 sacc[4][64];            // [wave][lane]
  const int n = blockIdx.x;
  const int t = threadIdx.x;
  const int lane = t & 63, w = t >> 6;
  const int h = t & 3, j0 = t >> 2;
  const int hd = lane >> 4;
  const int s0  = offs[n];
  const int deg = offs[n + 1] - s0;         // >= 1 (self-loops)
  const bool cached = (deg <= DCAP);

  if (cached) {
    const float ernh = er[n * HEADS + h];
    float dp = 0.f;
    for (int j = j0; j < deg; j += 64) {
      int s = csr_src[s0 + j];
      float sc = el[s * HEADS + h] + ernh;
      sc = sc > 0.f ? sc : NEG_SLOPE * sc;  // leaky_relu
      float wv = __expf(sc);
      sw4[j * 4 + h] = wv;
      if (h == 0) ssrc[j] = s;
      dp += wv;
    }
    #pragma unroll
    for (int off = 4; off < 64; off <<= 1) dp += __shfl_xor(dp, off);
    if (lane < 4) sden[w][lane] = dp;
  }
  __syncthreads();

  float4 acc = make_float4(0.f, 0.f, 0.f, 0.f);
  if (cached) {
    int j = w;
    for (; j + 4 < deg; j += 8) {           // 2-way unroll
      int   sa = ssrc[j],         sb = ssrc[j + 4];
      float wa = sw4[j * 4 + hd], wb = sw4[(j + 4) * 4 + hd];
      ushort4 fa = *((const ushort4*)&feat[(size_t)sa * HF] + lane);
      ushort4 fb = *((const ushort4*)&feat[(size_t)sb * HF] + lane);
      acc.x = fmaf(wa, bf2f(fa.x), acc.x); acc.x = fmaf(wb, bf2f(fb.x), acc.x);
      acc.y = fmaf(wa, bf2f(fa.y), acc.y); acc.y = fmaf(wb, bf2f(fb.y), acc.y);
      acc.z = fmaf(wa, bf2f(fa.z), acc.z); acc.z = fmaf(wb, bf2f(fb.z), acc.z);
      acc.w = fmaf(wa, bf2f(fa.w), acc.w); acc.w = fmaf(wb, bf2f(fb.w), acc.w);
    }
    if (j < deg) {
      int   sa = ssrc[j];
      float wa = sw4[j * 4 + hd];
      ushort4 fa = *((const ushort4*)&feat[(size_t)sa * HF] + lane);
      acc.x = fmaf(wa, bf2f(fa.x), acc.x);
      acc.y = fmaf(wa, bf2f(fa.y), acc.y);
      acc.z = fmaf(wa, bf2f(fa.z), acc.z);
      acc.w = fmaf(wa, bf2f(fa.w), acc.w);
    }
  } else {                                  // rare deg>128 fallback
    const float ernd = er[n * HEADS + hd];
    float dpu = 0.f;
    for (int j = w; j < deg; j += 4) {
      int s = csr_src[s0 + j];
      float sc = el[s * HEADS + hd] + ernd;
      sc = sc > 0.f ? sc : NEG_SLOPE * sc;
      float wv = __expf(sc);
      dpu += wv;
      ushort4 fa = *((const ushort4*)&feat[(size_t)s * HF] + lane);
      acc.x = fmaf(wv, bf2f(fa.x), acc.x);
      acc.y = fmaf(wv, bf2f(fa.y), acc.y);
      acc.z = fmaf(wv, bf2f(fa.z), acc.z);
      acc.w = fmaf(wv, bf2f(fa.w), acc.w);
    }
    if ((lane & 15) == 0) sden[w][hd] = dpu;
  }
  sacc[w][lane] = acc;
  __syncthreads();

  if (w == 0) {
    float4 a0 = sacc[0][lane], a1 = sacc[1][lane],
           a2 = sacc[2][lane], a3 = sacc[3][lane];
    float denom = sden[0][hd] + sden[1][hd] + sden[2][hd] + sden[3][hd];
    float rden = 1.f / denom;
    ushort4 rv = *((const ushort4*)&res[(size_t)n * HF] + lane);
    float4  bv = *((const float4*)bias + lane);
    float v0 = (a0.x + a1.x + a2.x + a3.x) * rden + bf2f(rv.x) + bv.x;
    float v1 = (a0.y + a1.y + a2.y + a3.y) * rden + bf2f(rv.y) + bv.y;
    float v2 = (a0.z + a1.z + a2.z + a3.z) * rden + bf2f(rv.z) + bv.z;
    float v3 = (a0.w + a1.w + a2.w + a3.w) * rden + bf2f(rv.w) + bv.w;
    v0 = v0 > 0.f ? v0 : expm1f(v0);        // ELU(alpha=1)
    v1 = v1 > 0.f ? v1 : expm1f(v1);
    v2 = v2 > 0.f ? v2 : expm1f(v2);
    v3 = v3 > 0.f ? v3 : expm1f(v3);
    ushort4 o;
    o.x = f2bf(v0); o.y = f2bf(v1); o.z = f2bf(v2); o.w = f2bf(v3);
    *((ushort4*)&outbf[(size_t)n * HF] + lane) = o;
  }
}

// ---------------------------------------------------------------------------
// GAT aggregation layer 2 — same core; epilogue writes the f32 h2 row plus
// node_w[n] = sigmoid(dot(h2row, Ww)+bw). No atomics (gid sorted; per-graph
// reduction in k_rp).
// ---------------------------------------------------------------------------
__global__ __launch_bounds__(256) void agg_l2(
    const unsigned short* __restrict__ feat, const unsigned short* __restrict__ res,
    const float* __restrict__ el, const float* __restrict__ er,
    const float* __restrict__ bias, const int* __restrict__ csr_src,
    const int* __restrict__ offs, const float* __restrict__ Ww,
    const float* __restrict__ bw, float* __restrict__ h2out,
    float* __restrict__ node_w)
{
  __shared__ int    ssrc[DCAP];
  __shared__ float  sw4[DCAP * 4];
  __shared__ float  sden[4][4];
  __shared__ float4 sacc[4][64];
  const int n = blockIdx.x;
  const int t = threadIdx.x;
  const int lane = t & 63, w = t >> 6;
  const int h = t & 3, j0 = t >> 2;
  const int hd = lane >> 4;
  const int s0  = offs[n];
  const int deg = offs[n + 1] - s0;
  const bool cached = (deg <= DCAP);

  if (cached) {
    const float ernh = er[n * HEADS + h];
    float dp = 0.f;
    for (int j = j0; j < deg; j += 64) {
      int s = csr_src[s0 + j];
      float sc = el[s * HEADS + h] + ernh;
      sc = sc > 0.f ? sc : NEG_SLOPE * sc;
      float wv = __expf(sc);
      sw4[j * 4 + h] = wv;
      if (h == 0) ssrc[j] = s;
      dp += wv;
    }
    #pragma unroll
    for (int off = 4; off < 64; off <<= 1) dp += __shfl_xor(dp, off);
    if (lane < 4) sden[w][lane] = dp;
  }
  __syncthreads();

  float4 acc = make_float4(0.f, 0.f, 0.f, 0.f);
  if (cached) {
    int j = w;
    for (; j + 4 < deg; j += 8) {
      int   sa = ssrc[j],         sb = ssrc[j + 4];
      float wa = sw4[j * 4 + hd], wb = sw4[(j + 4) * 4 + hd];
      ushort4 fa = *((const ushort4*)&feat[(size_t)sa * HF] + lane);
      ushort4 fb = *((const ushort4*)&feat[(size_t)sb * HF] + lane);
      acc.x = fmaf(wa, bf2f(fa.x), acc.x); acc.x = fmaf(wb, bf2f(fb.x), acc.x);
      acc.y = fmaf(wa, bf2f(fa.y), acc.y); acc.y = fmaf(wb, bf2f(fb.y), acc.y);
      acc.z = fmaf(wa, bf2f(fa.z), acc.z); acc.z = fmaf(wb, bf2f(fb.z), acc.z);
      acc.w = fmaf(wa, bf2f(fa.w), acc.w); acc.w = fmaf(wb, bf2f(fb.w), acc.w);
    }
    if (j < deg) {
      int   sa = ssrc[j];
      float wa = sw4[j * 4 + hd];
      ushort4 fa = *((const ushort4*)&feat[(size_t)sa * HF] + lane);
      acc.x = fmaf(wa, bf2f(fa.x), acc.x);
      acc.y = fmaf(wa, bf2f(fa.y), acc.y);
      acc.z = fmaf(wa, bf2f(fa.z), acc.z);
      acc.w = fmaf(wa, bf2f(fa.w), acc.w);
    }
  } else {
    const float ernd = er[n * HEADS + hd];
    float dpu = 0.f;
    for (int j = w; j < deg; j += 4) {
      int s = csr_src[s0 + j];
      float sc = el[s * HEADS + hd] + ernd;
      sc = sc > 0.f ? sc : NEG_SLOPE * sc;
      float wv = __expf(sc);
      dpu += wv;
      ushort4 fa = *((const ushort4*)&feat[(size_t)s * HF] + lane);
      acc.x = fmaf(wv, bf2f(fa.x), acc.x);
      acc.y = fmaf(wv, bf2f(fa.y), acc.y);
      acc.z = fmaf(wv, bf2f(fa.z), acc.z);
      acc.w = fmaf(wv, bf2f(fa.w), acc.w);
    }
    if ((lane & 15) == 0) sden[w][hd] = dpu;
  }
  sacc[w][lane] = acc;
  __syncthreads();

  if (w == 0) {
    float4 a0 = sacc[0][lane], a1 = sacc[1][lane],
           a2 = sacc[2][lane], a3 = sacc[3][lane];
    float denom = sden[0][hd] + sden[1][hd] + sden[2][hd] + sden[3][hd];
    float rden = 1.f / denom;
    ushort4 rv = *((const ushort4*)&res[(size_t)n * HF] + lane);
    float4  bv = *((const float4*)bias + lane);
    float v0 = (a0.x + a1.x + a2.x + a3.x) * rden + bf2f(rv.x) + bv.x;
    float v1 = (a0.y + a1.y + a2.y + a3.y) * rden + bf2f(rv.y) + bv.y;
    float v2 = (a0.z + a1.z + a2.z + a3.z) * rden + bf2f(rv.z) + bv.z;
    float v3 = (a0.w + a1.w + a2.w + a3.w) * rden + bf2f(rv.w) + bv.w;
    v0 = v0 > 0.f ? v0 : expm1f(v0);        // ELU(alpha=1)
    v1 = v1 > 0.f ? v1 : expm1f(v1);
    v2 = v2 > 0.f ? v2 : expm1f(v2);
    v3 = v3 > 0.f ? v3 : expm1f(v3);
    #pragma unroll
    for (int off = 16; off < 64; off <<= 1) {     // sum across the 4 heads
      v0 += __shfl_xor(v0, off);
      v1 += __shfl_xor(v1, off);
      v2 += __shfl_xor(v2, off);
      v3 += __shfl_xor(v3, off);
    }
    if (lane < 16) {                        // h2 row lives in lanes 0-15
      const float m0 = 0.25f * v0, m1 = 0.25f * v1,
                  m2 = 0.25f * v2, m3 = 0.25f * v3;
      *((float4*)&h2out[(size_t)n * FD] + lane) = make_float4(m0, m1, m2, m3);
      const float4 wwv = ((const float4*)Ww)[lane];
      float part = m0 * wwv.x + m1 * wwv.y + m2 * wwv.z + m3 * wwv.w;
      #pragma unroll
      for (int off = 1; off < 16; off <<= 1)
        part += __shfl_xor(part, off);
      if (lane == 0)
        node_w[n] = 1.f / (1.f + __expf(-(part + bw[0])));
    }
  }
}

// ---------------------------------------------------------------------------
// Fused per-graph readout + predictor: one WAVE per graph (gid sorted ->
// contiguous node range via goffs, zero atomics). Lane f streams wsum/hmax;
// gfeat staged in LDS; lanes 0-31 compute the 32 hidden units; shfl-reduce
// the final dot. Empty graphs: ws=0, mx=-inf (JAX segment semantics).
// ---------------------------------------------------------------------------
__global__ __launch_bounds__(256) void k_rp(
    const float* __restrict__ h2, const float* __restrict__ node_w,
    const int* __restrict__ goffs,
    const float* __restrict__ Wp1, const float* __restrict__ bp1,
    const float* __restrict__ Wp2, const float* __restrict__ bp2,
    float* __restrict__ out, int G)
{
  __shared__ float lws[4][FD];
  __shared__ float lmx[4][FD];
  const int w = threadIdx.x >> 6, lane = threadIdx.x & 63;
  const int g = blockIdx.x * 4 + w;

  float ws = 0.f, mx = -INFINITY;
  if (g < G) {
    const int n0 = goffs[g], n1 = goffs[g + 1];
    for (int n = n0; n < n1; ++n) {
      float v  = h2[(size_t)n * FD + lane];
      float wn = node_w[n];
      ws = fmaf(wn, v, ws);
      mx = fmaxf(mx, v);
    }
  }
  lws[w][lane] = ws;
  lmx[w][lane] = mx;
  __syncthreads();

  float acc = 0.f;
  if (g < G && lane < 32) {
    acc = bp1[lane];
    #pragma unroll 4
    for (int k = 0; k < FD; ++k)
      acc = fmaf(lws[w][k], Wp1[k * 32 + lane], acc);
    #pragma unroll 4
    for (int k = 0; k < FD; ++k)
      acc = fmaf(lmx[w][k], Wp1[(FD + k) * 32 + lane], acc);
    acc = fmaxf(acc, 0.f) * Wp2[lane];
  }
  #pragma unroll
  for (int off = 1; off < 32; off <<= 1)    // reduce lanes 0-31
    acc += __shfl_xor(acc, off);
  if (g < G && lane == 0) out[g] = acc + bp2[0];
}

// ---------------------------------------------------------------------------
extern "C" void kernel_launch(void* const* d_in, const int* in_sizes, int n_in,
                              void* d_out, int out_size, void* d_ws, size_t ws_size,
                              hipStream_t stream) {
  const float* x     = (const float*)d_in[0];
  const int*   src   = (const int*)  d_in[1];
  const int*   dst   = (const int*)  d_in[2];
  const int*   gid   = (const int*)  d_in[3];
  const float* W1    = (const float*)d_in[4];
  const float* al1   = (const float*)d_in[5];
  const float* ar1   = (const float*)d_in[6];
  const float* b1    = (const float*)d_in[7];
  const float* Wres1 = (const float*)d_in[8];
  const float* W2    = (const float*)d_in[9];
  const float* al2   = (const float*)d_in[10];
  const float* ar2   = (const float*)d_in[11];
  const float* b2    = (const float*)d_in[12];
  const float* Wres2 = (const float*)d_in[13];
  const float* Ww    = (const float*)d_in[14];
  const float* bw    = (const float*)d_in[15];
  const float* Wp1   = (const float*)d_in[16];
  const float* bp1   = (const float*)d_in[17];
  const float* Wp2   = (const float*)d_in[18];
  const float* bp2   = (const float*)d_in[19];
  float* out = (float*)d_out;

  const int N = in_sizes[3];        // gid has N elements
  const int E = in_sizes[1];        // src has E elements
  const int G = out_size;           // output is [G,1]
  const int Mpad = (N + 127) & ~127;

  // ---- workspace carve (256B-aligned) ----
  char* p = (char*)d_ws;
  auto alloc = [&](size_t bytes) {
    char* r = p;
    p += (bytes + 255) & ~(size_t)255;
    return r;
  };
  unsigned short* featbf  = (unsigned short*)alloc((size_t)Mpad * HF * 2);
  unsigned short* resbf   = (unsigned short*)alloc((size_t)Mpad * HF * 2);
  float*          el      = (float*)         alloc((size_t)N * HEADS * 4);
  float*          er      = (float*)         alloc((size_t)N * HEADS * 4);
  int*            counts  = (int*)           alloc((size_t)N * 4);
  int*            cursor  = (int*)           alloc((size_t)N * 4);
  int*            offs    = (int*)           alloc((size_t)(N + 1) * 4);
  const int nb            = (N + 1023) / 1024;
  int*            bsum    = (int*)           alloc((size_t)nb * 4);
  int*            csr_src = (int*)           alloc((size_t)E * 4);
  float*          h2      = (float*)         alloc((size_t)N * FD * 4);
  float*          node_w  = (float*)         alloc((size_t)N * 4);
  int*            goffs   = (int*)           alloc((size_t)(G + 1) * 4);
  unsigned short* xbf     = (unsigned short*)alloc((size_t)Mpad * 64 * 2);
  unsigned short* h1bf    = (unsigned short*)alloc((size_t)Mpad * HF * 2);
  unsigned short* BT1     = (unsigned short*)alloc((size_t)512 * 64 * 2);
  unsigned short* BT2     = (unsigned short*)alloc((size_t)512 * 256 * 2);
  (void)ws_size; (void)n_in;

  // ---- conversions + scratch init + goffs build (one kernel) ----
  const int n4 = N * 64 / 4;
  const int init_total = n4 + 512 * 64 + 512 * 256 + N + N + N;
  k_cvt_init<<<(init_total + 255) / 256, 256, 0, stream>>>(
      x, W1, Wres1, W2, Wres2, xbf, BT1, BT2,
      counts, cursor, gid, goffs, n4, N, G);

  // ---- CSR by destination (shared by both layers) ----
  k_hist   <<<(E + 255) / 256, 256, 0, stream>>>(dst, counts, E);
  k_scan1  <<<nb, 256, 0, stream>>>(counts, offs, bsum, N);
  k_scan2  <<<1, 64, 0, stream>>>(bsum, nb, offs, N);
  k_scan3  <<<(N + 255) / 256, 256, 0, stream>>>(offs, bsum, N);
  k_scatter<<<(E + 255) / 256, 256, 0, stream>>>(src, dst, offs, cursor, csr_src, E);

  // A-tile-sharing column-blocks dispatch adjacently (x fastest-varying).
  dim3 gg(4, Mpad / 128);

  // ---- layer 1 (flatten) ----
  gemm_mfma<64> <<<gg, 256, 0, stream>>>(xbf, BT1, al1, ar1,
                                         featbf, resbf, el, er, N);
  agg_l1        <<<N, 256, 0, stream>>>(featbf, resbf, el, er, b1, csr_src,
                                        offs, h1bf);

  // ---- layer 2 (mean) ----
  gemm_mfma<256><<<gg, 256, 0, stream>>>(h1bf, BT2, al2, ar2,
                                         featbf, resbf, el, er, N);
  agg_l2        <<<N, 256, 0, stream>>>(featbf, resbf, el, er, b2, csr_src,
                                        offs, Ww, bw, h2, node_w);

  // ---- fused per-graph readout + predictor (no atomics) ----
  k_rp<<<(G + 3) / 4, 256, 0, stream>>>(h2, node_w, goffs,
                                        Wp1, bp1, Wp2, bp2, out, G);
}

// Round 17
// 339.587 us; speedup vs baseline: 1.1170x; 1.0435x over previous
//
#include <hip/hip_runtime.h>
#include <hip/hip_bf16.h>
#include <math.h>

// Problem constants (from reference): H=4 heads, F=64 per-head, H*F=256.
#define HF    256
#define HEADS 4
#define FD    64
#define NEG_SLOPE 0.2f

typedef __attribute__((ext_vector_type(8))) short short8;
typedef __attribute__((ext_vector_type(4))) float f32x4;

__device__ __forceinline__ float wave_sum(float v) {
  #pragma unroll
  for (int off = 32; off; off >>= 1) v += __shfl_xor(v, off);
  return v;
}

// f32 -> bf16 round-to-nearest-even (raw bits).
__device__ __forceinline__ unsigned short f2bf(float f) {
  unsigned u = __float_as_uint(f);
  u += 0x7FFFu + ((u >> 16) & 1u);
  return (unsigned short)(u >> 16);
}
__device__ __forceinline__ float bf2f(unsigned short u) {
  return __uint_as_float((unsigned)u << 16);
}

// async global->LDS, 16 B per lane (wave-uniform LDS base + lane*16).
__device__ __forceinline__ void gload_lds16(const void* g, void* l) {
  __builtin_amdgcn_global_load_lds((const unsigned int*)g, (unsigned int*)l,
                                   16, 0, 0);
}

// ---------------------------------------------------------------------------
// bf16 MFMA GEMM: C[Mpad x 512] = A[Mpad x K] @ B[K x 512], B given
// pre-transposed as BT[512 x K]. Output cols 0..255 -> featbf, 256..511 ->
// resbf (both bf16). For the feat half, each wave owns exactly one head's 64
// columns -> el/er computed in-register (16-lane shfl reduce over f32 acc).
// 128x128 tile, 4 waves (2x2), 4x4 fragments of 16x16x32, BK=32 (m97-lite).
// Grid: (Mpad/128, 4) — row-tile fastest (round-14 proven; the round-16
// col-fast swizzle cost +16 us: XCD round-robin put the 4 A-sharers on 4
// DIFFERENT L2s and destroyed the B-panel residency that the row-fast order
// gives for free).
// ---------------------------------------------------------------------------
template<int K>
__global__ __launch_bounds__(256) void gemm_mfma(
    const unsigned short* __restrict__ A,   // [Mpad][K] bf16 bits
    const unsigned short* __restrict__ BT,  // [512][K]  bf16 bits
    const float* __restrict__ al, const float* __restrict__ ar,
    unsigned short* __restrict__ featbf, unsigned short* __restrict__ resbf,
    float* __restrict__ el, float* __restrict__ er, int M)
{
  __shared__ __align__(16) unsigned short As[128 * 32];
  __shared__ __align__(16) unsigned short Bs[128 * 32];
  const int t    = threadIdx.x;
  const int lane = t & 63, w = t >> 6;
  const int wr = w >> 1, wc = w & 1;
  const int l15 = lane & 15, lhi = lane >> 4;
  const int row0 = blockIdx.x * 128;
  const int n0b  = blockIdx.y;             // 0,1 -> feat; 2,3 -> res

  // staging chunks: 512 chunks of 16B per tile; chunk c: row=c>>2, col8=(c&3)*8
  const int c0 = w * 128 + lane;
  const int c1 = c0 + 64;
  const unsigned short* gA0 = A  + (size_t)(row0 + (c0 >> 2)) * K + (c0 & 3) * 8;
  const unsigned short* gA1 = A  + (size_t)(row0 + (c1 >> 2)) * K + (c1 & 3) * 8;
  const unsigned short* gB0 = BT + (size_t)(n0b * 128 + (c0 >> 2)) * K + (c0 & 3) * 8;
  const unsigned short* gB1 = BT + (size_t)(n0b * 128 + (c1 >> 2)) * K + (c1 & 3) * 8;
  unsigned short* lA0 = &As[w * 1024];
  unsigned short* lA1 = &As[w * 1024 + 512];
  unsigned short* lB0 = &Bs[w * 1024];
  unsigned short* lB1 = &Bs[w * 1024 + 512];

  f32x4 acc[4][4];
  #pragma unroll
  for (int i = 0; i < 4; ++i)
    #pragma unroll
    for (int j = 0; j < 4; ++j)
      acc[i][j] = (f32x4){0.f, 0.f, 0.f, 0.f};

  for (int k0 = 0; k0 < K; k0 += 32) {
    __syncthreads();                       // prev iter's ds_reads done
    gload_lds16(gA0 + k0, lA0);
    gload_lds16(gA1 + k0, lA1);
    gload_lds16(gB0 + k0, lB0);
    gload_lds16(gB1 + k0, lB1);
    __syncthreads();                       // drains vmcnt -> LDS tiles ready

    short8 a[4], b[4];
    #pragma unroll
    for (int im = 0; im < 4; ++im)
      a[im] = *(const short8*)&As[(wr * 64 + im * 16 + l15) * 32 + lhi * 8];
    #pragma unroll
    for (int jn = 0; jn < 4; ++jn)
      b[jn] = *(const short8*)&Bs[(wc * 64 + jn * 16 + l15) * 32 + lhi * 8];
    #pragma unroll
    for (int im = 0; im < 4; ++im)
      #pragma unroll
      for (int jn = 0; jn < 4; ++jn)
        acc[im][jn] = __builtin_amdgcn_mfma_f32_16x16x32_bf16(
            a[im], b[jn], acc[im][jn], 0, 0, 0);
  }

  // C/D layout: col = lane&15, row = (lane>>4)*4 + q   [m89/m91 verified]
  unsigned short* outp = (n0b < 2) ? featbf : resbf;
  const int colbase = (n0b & 1) * 128 + wc * 64;
  #pragma unroll
  for (int im = 0; im < 4; ++im) {
    const int rowb = row0 + wr * 64 + im * 16 + lhi * 4;
    #pragma unroll
    for (int q = 0; q < 4; ++q) {
      if (rowb + q < M) {
        unsigned short* rp = outp + (size_t)(rowb + q) * HF + colbase;
        #pragma unroll
        for (int jn = 0; jn < 4; ++jn)
          rp[jn * 16 + l15] = f2bf(acc[im][jn][q]);
      }
    }
  }

  // el/er for the feat half: wave (n0b,wc) owns head hd's full 64 columns.
  if (n0b < 2) {
    const int hd = n0b * 2 + wc;
    float alv[4], arv[4];
    #pragma unroll
    for (int jn = 0; jn < 4; ++jn) {
      alv[jn] = al[hd * FD + jn * 16 + l15];
      arv[jn] = ar[hd * FD + jn * 16 + l15];
    }
    #pragma unroll
    for (int im = 0; im < 4; ++im) {
      #pragma unroll
      for (int q = 0; q < 4; ++q) {
        float es = 0.f, rs = 0.f;
        #pragma unroll
        for (int jn = 0; jn < 4; ++jn) {
          es = fmaf(acc[im][jn][q], alv[jn], es);
          rs = fmaf(acc[im][jn][q], arv[jn], rs);
        }
        #pragma unroll
        for (int off = 1; off < 16; off <<= 1) {   // reduce across l15 group
          es += __shfl_xor(es, off);
          rs += __shfl_xor(rs, off);
        }
        const int row = row0 + wr * 64 + im * 16 + lhi * 4 + q;
        if (l15 == 0 && row < M) {
          el[row * HEADS + hd] = es;
          er[row * HEADS + hd] = rs;
        }
      }
    }
  }
}

// ---------------------------------------------------------------------------
// Fused conversions + scratch init + graph-offset build (gid is SORTED):
// x->bf16 | BT1 | BT2 | counts=0 | cursor=0 | goffs boundary-fill.
// goffs[g] = first node index with gid >= g; graph g = [goffs[g], goffs[g+1]).
// ---------------------------------------------------------------------------
__global__ void k_cvt_init(
    const float* __restrict__ x,
    const float* __restrict__ W1, const float* __restrict__ Wres1,
    const float* __restrict__ W2, const float* __restrict__ Wres2,
    unsigned short* __restrict__ xbf, unsigned short* __restrict__ BT1,
    unsigned short* __restrict__ BT2, int* __restrict__ counts,
    int* __restrict__ cursor, const int* __restrict__ gid,
    int* __restrict__ goffs, int n4, int N, int G)
{
  int i = blockIdx.x * 256 + threadIdx.x;
  if (i < n4) {
    float4 v = ((const float4*)x)[i];
    ushort4 o;
    o.x = f2bf(v.x); o.y = f2bf(v.y); o.z = f2bf(v.z); o.w = f2bf(v.w);
    ((ushort4*)xbf)[i] = o;
    return;
  }
  i -= n4;
  if (i < 512 * 64) {
    int j = i >> 6, k = i & 63;
    float v = (j < HF) ? W1[k * HF + j] : Wres1[k * HF + (j - HF)];
    BT1[i] = f2bf(v);
    return;
  }
  i -= 512 * 64;
  if (i < 512 * 256) {
    int j = i >> 8, k = i & 255;
    float v = (j < HF) ? W2[k * HF + j] : Wres2[k * HF + (j - HF)];
    BT2[i] = f2bf(v);
    return;
  }
  i -= 512 * 256;
  if (i < N) { counts[i] = 0; return; }
  i -= N;
  if (i < N) { cursor[i] = 0; return; }
  i -= N;
  if (i < N) {
    const int g1 = gid[i];
    if (i == 0) {
      for (int g = 0; g <= g1; ++g) goffs[g] = 0;
    } else {
      const int g0 = gid[i - 1];
      for (int g = g0 + 1; g <= g1; ++g) goffs[g] = i;
    }
    if (i == N - 1) {
      for (int g = g1 + 1; g <= G; ++g) goffs[g] = N;
    }
  }
}

// ---------------------------------------------------------------------------
// CSR build: histogram -> 2-level exclusive scan -> scatter.
// ---------------------------------------------------------------------------
__global__ void k_hist(const int* __restrict__ dst, int* __restrict__ counts, int E) {
  int i = blockIdx.x * 256 + threadIdx.x;
  if (i < E) atomicAdd(&counts[dst[i]], 1);
}

__global__ __launch_bounds__(256) void k_scan1(
    const int* __restrict__ counts, int* __restrict__ offs,
    int* __restrict__ bsum, int n)
{
  __shared__ int lds[256];
  const int b = blockIdx.x, t = threadIdx.x;
  const int base = b * 1024 + t * 4;
  int v[4];
  #pragma unroll
  for (int i = 0; i < 4; ++i) { int idx = base + i; v[i] = (idx < n) ? counts[idx] : 0; }
  int tsum = v[0] + v[1] + v[2] + v[3];
  lds[t] = tsum;
  __syncthreads();
  for (int off = 1; off < 256; off <<= 1) {
    int x = (t >= off) ? lds[t - off] : 0;
    __syncthreads();
    lds[t] += x;
    __syncthreads();
  }
  int run = lds[t] - tsum;
  #pragma unroll
  for (int i = 0; i < 4; ++i) {
    int idx = base + i;
    if (idx < n) offs[idx] = run;
    run += v[i];
  }
  if (t == 255) bsum[b] = lds[255];
}

// Wave-parallel block-sum scan (nb <= 64 on this problem; serial fallback).
__global__ void k_scan2(int* __restrict__ bsum, int nb, int* __restrict__ offs, int n) {
  const int t = threadIdx.x;                  // 64 threads
  if (nb <= 64) {
    int v = (t < nb) ? bsum[t] : 0;
    int inc = v;
    #pragma unroll
    for (int off = 1; off < 64; off <<= 1) {
      int u = __shfl_up(inc, off);
      if (t >= off) inc += u;
    }
    if (t < nb) bsum[t] = inc - v;            // exclusive prefix
    int total = __shfl(inc, 63);
    if (t == 0) offs[n] = total;              // == E
  } else if (t == 0) {
    int run = 0;
    for (int b = 0; b < nb; ++b) { int x = bsum[b]; bsum[b] = run; run += x; }
    offs[n] = run;
  }
}

__global__ void k_scan3(int* __restrict__ offs, const int* __restrict__ bsum, int n) {
  int i = blockIdx.x * 256 + threadIdx.x;
  if (i < n) offs[i] += bsum[i >> 10];
}

__global__ void k_scatter(const int* __restrict__ src, const int* __restrict__ dst,
                          const int* __restrict__ offs, int* __restrict__ cursor,
                          int* __restrict__ csr_src, int E) {
  int i = blockIdx.x * 256 + threadIdx.x;
  if (i < E) {
    int d = dst[i];
    int pos = offs[d] + atomicAdd(&cursor[d], 1);
    csr_src[pos] = src[i];
  }
}

// ---------------------------------------------------------------------------
// GAT aggregation layer 1 (round-14 core, ONE barrier).
//   Pass 1 NEW LAYOUT: wave w scores exactly the edges j == w (mod 4) it
//   will gather in pass 2 (lane = 4*e + h -> j = w + 4*e, head h). All
//   sw4/ssrc entries pass 2 reads are same-wave writes -> the old mid-kernel
//   __syncthreads() is unnecessary (per-wave LDS ops are in-order; compiler
//   inserts lgkmcnt waits). Per-head denom partials -> sden[w][h], summed in
//   the epilogue after the single remaining barrier.
//   No max-subtraction (scores O(+-3), exp f32-safe, softmax ratio identical).
//   Pass 2: wave w walks its edges; lane loads ushort4 (its 4 features of the
//   512 B row, head = lane>>4); weight = LDS broadcast; f32 acc, 2-way unroll.
//   Epilogue (wave 0): sum 4 waves, /denom, +res, +bias, ELU -> bf16 h1 row.
// ---------------------------------------------------------------------------
#define DCAP 128
__global__ __launch_bounds__(256) void agg_l1(
    const unsigned short* __restrict__ feat, const unsigned short* __restrict__ res,
    const float* __restrict__ el, const float* __restrict__ er,
    const float* __restrict__ bias, const int* __restrict__ csr_src,
    const int* __restrict__ offs, unsigned short* __restrict__ outbf)
{
  __shared__ int    ssrc[DCAP];
  __shared__ float  sw4[DCAP * 4];          // [j][h]
  __shared__ float  sden[4][4];             // [wave][h]
  __shared__ float4 sacc[4][64];            // [wave][lane]
  const int n = blockIdx.x;
  const int t = threadIdx.x;
  const int lane = t & 63, w = t >> 6;
  const int h = lane & 3, e0 = lane >> 2;   // pass-1 layout (wave-owned j)
  const int hd = lane >> 4;                 // pass-2 head
  const int s0  = offs[n];
  const int deg = offs[n + 1] - s0;         // >= 1 (self-loops)
  const bool cached = (deg <= DCAP);

  if (cached) {
    const float ernh = er[n * HEADS + h];
    float dp = 0.f;
    for (int j = w + 4 * e0; j < deg; j += 64) {
      int s = csr_src[s0 + j];
      float sc = el[s * HEADS + h] + ernh;
      sc = sc > 0.f ? sc : NEG_SLOPE * sc;  // leaky_relu
      float wv = __expf(sc);
      sw4[j * 4 + h] = wv;
      if (h == 0) ssrc[j] = s;
      dp += wv;
    }
    #pragma unroll
    for (int off = 4; off < 64; off <<= 1) dp += __shfl_xor(dp, off);
    if (lane < 4) sden[w][lane] = dp;
  }
  // NO mid barrier: wave w reads only its own sw4/ssrc writes below.

  float4 acc = make_float4(0.f, 0.f, 0.f, 0.f);
  if (cached) {
    int j = w;
    for (; j + 4 < deg; j += 8) {           // 2-way unroll
      int   sa = ssrc[j],         sb = ssrc[j + 4];
      float wa = sw4[j * 4 + hd], wb = sw4[(j + 4) * 4 + hd];
      ushort4 fa = *((const ushort4*)&feat[(size_t)sa * HF] + lane);
      ushort4 fb = *((const ushort4*)&feat[(size_t)sb * HF] + lane);
      acc.x = fmaf(wa, bf2f(fa.x), acc.x); acc.x = fmaf(wb, bf2f(fb.x), acc.x);
      acc.y = fmaf(wa, bf2f(fa.y), acc.y); acc.y = fmaf(wb, bf2f(fb.y), acc.y);
      acc.z = fmaf(wa, bf2f(fa.z), acc.z); acc.z = fmaf(wb, bf2f(fb.z), acc.z);
      acc.w = fmaf(wa, bf2f(fa.w), acc.w); acc.w = fmaf(wb, bf2f(fb.w), acc.w);
    }
    if (j < deg) {
      int   sa = ssrc[j];
      float wa = sw4[j * 4 + hd];
      ushort4 fa = *((const ushort4*)&feat[(size_t)sa * HF] + lane);
      acc.x = fmaf(wa, bf2f(fa.x), acc.x);
      acc.y = fmaf(wa, bf2f(fa.y), acc.y);
      acc.z = fmaf(wa, bf2f(fa.z), acc.z);
      acc.w = fmaf(wa, bf2f(fa.w), acc.w);
    }
  } else {                                  // rare deg>128 fallback
    const float ernd = er[n * HEADS + hd];
    float dpu = 0.f;
    for (int j = w; j < deg; j += 4) {
      int s = csr_src[s0 + j];
      float sc = el[s * HEADS + hd] + ernd;
      sc = sc > 0.f ? sc : NEG_SLOPE * sc;
      float wv = __expf(sc);
      dpu += wv;
      ushort4 fa = *((const ushort4*)&feat[(size_t)s * HF] + lane);
      acc.x = fmaf(wv, bf2f(fa.x), acc.x);
      acc.y = fmaf(wv, bf2f(fa.y), acc.y);
      acc.z = fmaf(wv, bf2f(fa.z), acc.z);
      acc.w = fmaf(wv, bf2f(fa.w), acc.w);
    }
    if ((lane & 15) == 0) sden[w][hd] = dpu;
  }
  sacc[w][lane] = acc;
  __syncthreads();

  if (w == 0) {
    float4 a0 = sacc[0][lane], a1 = sacc[1][lane],
           a2 = sacc[2][lane], a3 = sacc[3][lane];
    float denom = sden[0][hd] + sden[1][hd] + sden[2][hd] + sden[3][hd];
    float rden = 1.f / denom;
    ushort4 rv = *((const ushort4*)&res[(size_t)n * HF] + lane);
    float4  bv = *((const float4*)bias + lane);
    float v0 = (a0.x + a1.x + a2.x + a3.x) * rden + bf2f(rv.x) + bv.x;
    float v1 = (a0.y + a1.y + a2.y + a3.y) * rden + bf2f(rv.y) + bv.y;
    float v2 = (a0.z + a1.z + a2.z + a3.z) * rden + bf2f(rv.z) + bv.z;
    float v3 = (a0.w + a1.w + a2.w + a3.w) * rden + bf2f(rv.w) + bv.w;
    v0 = v0 > 0.f ? v0 : expm1f(v0);        // ELU(alpha=1)
    v1 = v1 > 0.f ? v1 : expm1f(v1);
    v2 = v2 > 0.f ? v2 : expm1f(v2);
    v3 = v3 > 0.f ? v3 : expm1f(v3);
    ushort4 o;
    o.x = f2bf(v0); o.y = f2bf(v1); o.z = f2bf(v2); o.w = f2bf(v3);
    *((ushort4*)&outbf[(size_t)n * HF] + lane) = o;
  }
}

// ---------------------------------------------------------------------------
// GAT aggregation layer 2 — same one-barrier core; epilogue writes the f32
// h2 row + node_w[n] = sigmoid(dot(h2row, Ww)+bw). No atomics (gid sorted;
// per-graph reduction in k_rp).
// ---------------------------------------------------------------------------
__global__ __launch_bounds__(256) void agg_l2(
    const unsigned short* __restrict__ feat, const unsigned short* __restrict__ res,
    const float* __restrict__ el, const float* __restrict__ er,
    const float* __restrict__ bias, const int* __restrict__ csr_src,
    const int* __restrict__ offs, const float* __restrict__ Ww,
    const float* __restrict__ bw, float* __restrict__ h2out,
    float* __restrict__ node_w)
{
  __shared__ int    ssrc[DCAP];
  __shared__ float  sw4[DCAP * 4];
  __shared__ float  sden[4][4];
  __shared__ float4 sacc[4][64];
  const int n = blockIdx.x;
  const int t = threadIdx.x;
  const int lane = t & 63, w = t >> 6;
  const int h = lane & 3, e0 = lane >> 2;   // pass-1 layout (wave-owned j)
  const int hd = lane >> 4;
  const int s0  = offs[n];
  const int deg = offs[n + 1] - s0;
  const bool cached = (deg <= DCAP);

  if (cached) {
    const float ernh = er[n * HEADS + h];
    float dp = 0.f;
    for (int j = w + 4 * e0; j < deg; j += 64) {
      int s = csr_src[s0 + j];
      float sc = el[s * HEADS + h] + ernh;
      sc = sc > 0.f ? sc : NEG_SLOPE * sc;
      float wv = __expf(sc);
      sw4[j * 4 + h] = wv;
      if (h == 0) ssrc[j] = s;
      dp += wv;
    }
    #pragma unroll
    for (int off = 4; off < 64; off <<= 1) dp += __shfl_xor(dp, off);
    if (lane < 4) sden[w][lane] = dp;
  }
  // NO mid barrier (same-wave LDS producer/consumer).

  float4 acc = make_float4(0.f, 0.f, 0.f, 0.f);
  if (cached) {
    int j = w;
    for (; j + 4 < deg; j += 8) {
      int   sa = ssrc[j],         sb = ssrc[j + 4];
      float wa = sw4[j * 4 + hd], wb = sw4[(j + 4) * 4 + hd];
      ushort4 fa = *((const ushort4*)&feat[(size_t)sa * HF] + lane);
      ushort4 fb = *((const ushort4*)&feat[(size_t)sb * HF] + lane);
      acc.x = fmaf(wa, bf2f(fa.x), acc.x); acc.x = fmaf(wb, bf2f(fb.x), acc.x);
      acc.y = fmaf(wa, bf2f(fa.y), acc.y); acc.y = fmaf(wb, bf2f(fb.y), acc.y);
      acc.z = fmaf(wa, bf2f(fa.z), acc.z); acc.z = fmaf(wb, bf2f(fb.z), acc.z);
      acc.w = fmaf(wa, bf2f(fa.w), acc.w); acc.w = fmaf(wb, bf2f(fb.w), acc.w);
    }
    if (j < deg) {
      int   sa = ssrc[j];
      float wa = sw4[j * 4 + hd];
      ushort4 fa = *((const ushort4*)&feat[(size_t)sa * HF] + lane);
      acc.x = fmaf(wa, bf2f(fa.x), acc.x);
      acc.y = fmaf(wa, bf2f(fa.y), acc.y);
      acc.z = fmaf(wa, bf2f(fa.z), acc.z);
      acc.w = fmaf(wa, bf2f(fa.w), acc.w);
    }
  } else {
    const float ernd = er[n * HEADS + hd];
    float dpu = 0.f;
    for (int j = w; j < deg; j += 4) {
      int s = csr_src[s0 + j];
      float sc = el[s * HEADS + hd] + ernd;
      sc = sc > 0.f ? sc : NEG_SLOPE * sc;
      float wv = __expf(sc);
      dpu += wv;
      ushort4 fa = *((const ushort4*)&feat[(size_t)s * HF] + lane);
      acc.x = fmaf(wv, bf2f(fa.x), acc.x);
      acc.y = fmaf(wv, bf2f(fa.y), acc.y);
      acc.z = fmaf(wv, bf2f(fa.z), acc.z);
      acc.w = fmaf(wv, bf2f(fa.w), acc.w);
    }
    if ((lane & 15) == 0) sden[w][hd] = dpu;
  }
  sacc[w][lane] = acc;
  __syncthreads();

  if (w == 0) {
    float4 a0 = sacc[0][lane], a1 = sacc[1][lane],
           a2 = sacc[2][lane], a3 = sacc[3][lane];
    float denom = sden[0][hd] + sden[1][hd] + sden[2][hd] + sden[3][hd];
    float rden = 1.f / denom;
    ushort4 rv = *((const ushort4*)&res[(size_t)n * HF] + lane);
    float4  bv = *((const float4*)bias + lane);
    float v0 = (a0.x + a1.x + a2.x + a3.x) * rden + bf2f(rv.x) + bv.x;
    float v1 = (a0.y + a1.y + a2.y + a3.y) * rden + bf2f(rv.y) + bv.y;
    float v2 = (a0.z + a1.z + a2.z + a3.z) * rden + bf2f(rv.z) + bv.z;
    float v3 = (a0.w + a1.w + a2.w + a3.w) * rden + bf2f(rv.w) + bv.w;
    v0 = v0 > 0.f ? v0 : expm1f(v0);        // ELU(alpha=1)
    v1 = v1 > 0.f ? v1 : expm1f(v1);
    v2 = v2 > 0.f ? v2 : expm1f(v2);
    v3 = v3 > 0.f ? v3 : expm1f(v3);
    #pragma unroll
    for (int off = 16; off < 64; off <<= 1) {     // sum across the 4 heads
      v0 += __shfl_xor(v0, off);
      v1 += __shfl_xor(v1, off);
      v2 += __shfl_xor(v2, off);
      v3 += __shfl_xor(v3, off);
    }
    if (lane < 16) {                        // h2 row lives in lanes 0-15
      const float m0 = 0.25f * v0, m1 = 0.25f * v1,
                  m2 = 0.25f * v2, m3 = 0.25f * v3;
      *((float4*)&h2out[(size_t)n * FD] + lane) = make_float4(m0, m1, m2, m3);
      const float4 wwv = ((const float4*)Ww)[lane];
      float part = m0 * wwv.x + m1 * wwv.y + m2 * wwv.z + m3 * wwv.w;
      #pragma unroll
      for (int off = 1; off < 16; off <<= 1)
        part += __shfl_xor(part, off);
      if (lane == 0)
        node_w[n] = 1.f / (1.f + __expf(-(part + bw[0])));
    }
  }
}

// ---------------------------------------------------------------------------
// Fused per-graph readout + predictor: one WAVE per graph (gid sorted ->
// contiguous node range via goffs, zero atomics). Lane f streams wsum/hmax;
// gfeat staged in LDS; lanes 0-31 compute the 32 hidden units; shfl-reduce
// the final dot. Empty graphs: ws=0, mx=-inf (JAX segment semantics).
// ---------------------------------------------------------------------------
__global__ __launch_bounds__(256) void k_rp(
    const float* __restrict__ h2, const float* __restrict__ node_w,
    const int* __restrict__ goffs,
    const float* __restrict__ Wp1, const float* __restrict__ bp1,
    const float* __restrict__ Wp2, const float* __restrict__ bp2,
    float* __restrict__ out, int G)
{
  __shared__ float lws[4][FD];
  __shared__ float lmx[4][FD];
  const int w = threadIdx.x >> 6, lane = threadIdx.x & 63;
  const int g = blockIdx.x * 4 + w;

  float ws = 0.f, mx = -INFINITY;
  if (g < G) {
    const int n0 = goffs[g], n1 = goffs[g + 1];
    for (int n = n0; n < n1; ++n) {
      float v  = h2[(size_t)n * FD + lane];
      float wn = node_w[n];
      ws = fmaf(wn, v, ws);
      mx = fmaxf(mx, v);
    }
  }
  lws[w][lane] = ws;
  lmx[w][lane] = mx;
  __syncthreads();

  float acc = 0.f;
  if (g < G && lane < 32) {
    acc = bp1[lane];
    #pragma unroll 4
    for (int k = 0; k < FD; ++k)
      acc = fmaf(lws[w][k], Wp1[k * 32 + lane], acc);
    #pragma unroll 4
    for (int k = 0; k < FD; ++k)
      acc = fmaf(lmx[w][k], Wp1[(FD + k) * 32 + lane], acc);
    acc = fmaxf(acc, 0.f) * Wp2[lane];
  }
  #pragma unroll
  for (int off = 1; off < 32; off <<= 1)    // reduce lanes 0-31
    acc += __shfl_xor(acc, off);
  if (g < G && lane == 0) out[g] = acc + bp2[0];
}

// ---------------------------------------------------------------------------
extern "C" void kernel_launch(void* const* d_in, const int* in_sizes, int n_in,
                              void* d_out, int out_size, void* d_ws, size_t ws_size,
                              hipStream_t stream) {
  const float* x     = (const float*)d_in[0];
  const int*   src   = (const int*)  d_in[1];
  const int*   dst   = (const int*)  d_in[2];
  const int*   gid   = (const int*)  d_in[3];
  const float* W1    = (const float*)d_in[4];
  const float* al1   = (const float*)d_in[5];
  const float* ar1   = (const float*)d_in[6];
  const float* b1    = (const float*)d_in[7];
  const float* Wres1 = (const float*)d_in[8];
  const float* W2    = (const float*)d_in[9];
  const float* al2   = (const float*)d_in[10];
  const float* ar2   = (const float*)d_in[11];
  const float* b2    = (const float*)d_in[12];
  const float* Wres2 = (const float*)d_in[13];
  const float* Ww    = (const float*)d_in[14];
  const float* bw    = (const float*)d_in[15];
  const float* Wp1   = (const float*)d_in[16];
  const float* bp1   = (const float*)d_in[17];
  const float* Wp2   = (const float*)d_in[18];
  const float* bp2   = (const float*)d_in[19];
  float* out = (float*)d_out;

  const int N = in_sizes[3];        // gid has N elements
  const int E = in_sizes[1];        // src has E elements
  const int G = out_size;           // output is [G,1]
  const int Mpad = (N + 127) & ~127;

  // ---- workspace carve (256B-aligned) ----
  char* p = (char*)d_ws;
  auto alloc = [&](size_t bytes) {
    char* r = p;
    p += (bytes + 255) & ~(size_t)255;
    return r;
  };
  unsigned short* featbf  = (unsigned short*)alloc((size_t)Mpad * HF * 2);
  unsigned short* resbf   = (unsigned short*)alloc((size_t)Mpad * HF * 2);
  float*          el      = (float*)         alloc((size_t)N * HEADS * 4);
  float*          er      = (float*)         alloc((size_t)N * HEADS * 4);
  int*            counts  = (int*)           alloc((size_t)N * 4);
  int*            cursor  = (int*)           alloc((size_t)N * 4);
  int*            offs    = (int*)           alloc((size_t)(N + 1) * 4);
  const int nb            = (N + 1023) / 1024;
  int*            bsum    = (int*)           alloc((size_t)nb * 4);
  int*            csr_src = (int*)           alloc((size_t)E * 4);
  float*          h2      = (float*)         alloc((size_t)N * FD * 4);
  float*          node_w  = (float*)         alloc((size_t)N * 4);
  int*            goffs   = (int*)           alloc((size_t)(G + 1) * 4);
  unsigned short* xbf     = (unsigned short*)alloc((size_t)Mpad * 64 * 2);
  unsigned short* h1bf    = (unsigned short*)alloc((size_t)Mpad * HF * 2);
  unsigned short* BT1     = (unsigned short*)alloc((size_t)512 * 64 * 2);
  unsigned short* BT2     = (unsigned short*)alloc((size_t)512 * 256 * 2);
  (void)ws_size; (void)n_in;

  // ---- conversions + scratch init + goffs build (one kernel) ----
  const int n4 = N * 64 / 4;
  const int init_total = n4 + 512 * 64 + 512 * 256 + N + N + N;
  k_cvt_init<<<(init_total + 255) / 256, 256, 0, stream>>>(
      x, W1, Wres1, W2, Wres2, xbf, BT1, BT2,
      counts, cursor, gid, goffs, n4, N, G);

  // ---- CSR by destination (shared by both layers) ----
  k_hist   <<<(E + 255) / 256, 256, 0, stream>>>(dst, counts, E);
  k_scan1  <<<nb, 256, 0, stream>>>(counts, offs, bsum, N);
  k_scan2  <<<1, 64, 0, stream>>>(bsum, nb, offs, N);
  k_scan3  <<<(N + 255) / 256, 256, 0, stream>>>(offs, bsum, N);
  k_scatter<<<(E + 255) / 256, 256, 0, stream>>>(src, dst, offs, cursor, csr_src, E);

  // Row-tile fastest (round-14 proven ordering).
  dim3 gg(Mpad / 128, 4);

  // ---- layer 1 (flatten) ----
  gemm_mfma<64> <<<gg, 256, 0, stream>>>(xbf, BT1, al1, ar1,
                                         featbf, resbf, el, er, N);
  agg_l1        <<<N, 256, 0, stream>>>(featbf, resbf, el, er, b1, csr_src,
                                        offs, h1bf);

  // ---- layer 2 (mean) ----
  gemm_mfma<256><<<gg, 256, 0, stream>>>(h1bf, BT2, al2, ar2,
                                         featbf, resbf, el, er, N);
  agg_l2        <<<N, 256, 0, stream>>>(featbf, resbf, el, er, b2, csr_src,
                                        offs, Ww, bw, h2, node_w);

  // ---- fused per-graph readout + predictor (no atomics) ----
  k_rp<<<(G + 3) / 4, 256, 0, stream>>>(h2, node_w, goffs,
                                        Wp1, bp1, Wp2, bp2, out, G);
}

// Round 18
// 338.656 us; speedup vs baseline: 1.1201x; 1.0027x over previous
//
#include <hip/hip_runtime.h>
#include <hip/hip_bf16.h>
#include <math.h>

// Problem constants (from reference): H=4 heads, F=64 per-head, H*F=256.
#define HF    256
#define HEADS 4
#define FD    64
#define NEG_SLOPE 0.2f

typedef __attribute__((ext_vector_type(8))) short short8;
typedef __attribute__((ext_vector_type(4))) float f32x4;

__device__ __forceinline__ float wave_sum(float v) {
  #pragma unroll
  for (int off = 32; off; off >>= 1) v += __shfl_xor(v, off);
  return v;
}

// f32 -> bf16 round-to-nearest-even (raw bits).
__device__ __forceinline__ unsigned short f2bf(float f) {
  unsigned u = __float_as_uint(f);
  u += 0x7FFFu + ((u >> 16) & 1u);
  return (unsigned short)(u >> 16);
}
__device__ __forceinline__ float bf2f(unsigned short u) {
  return __uint_as_float((unsigned)u << 16);
}

// async global->LDS, 16 B per lane (wave-uniform LDS base + lane*16).
__device__ __forceinline__ void gload_lds16(const void* g, void* l) {
  __builtin_amdgcn_global_load_lds((const unsigned int*)g, (unsigned int*)l,
                                   16, 0, 0);
}

// ---------------------------------------------------------------------------
// bf16 MFMA GEMM: C[Mpad x 512] = A[Mpad x K] @ B[K x 512], B given
// pre-transposed as BT[512 x K]. Output cols 0..255 -> featbf, 256..511 ->
// resbf (both bf16). For the feat half, each wave owns exactly one head's 64
// columns -> el/er computed in-register (16-lane shfl reduce over f32 acc).
// 128x128 tile, 4 waves (2x2), 4x4 fragments of 16x16x32, BK=32 (m97-lite).
// Grid: (Mpad/128, 4) — row-tile fastest (round-14 proven ordering).
// ---------------------------------------------------------------------------
template<int K>
__global__ __launch_bounds__(256) void gemm_mfma(
    const unsigned short* __restrict__ A,   // [Mpad][K] bf16 bits
    const unsigned short* __restrict__ BT,  // [512][K]  bf16 bits
    const float* __restrict__ al, const float* __restrict__ ar,
    unsigned short* __restrict__ featbf, unsigned short* __restrict__ resbf,
    float* __restrict__ el, float* __restrict__ er, int M)
{
  __shared__ __align__(16) unsigned short As[128 * 32];
  __shared__ __align__(16) unsigned short Bs[128 * 32];
  const int t    = threadIdx.x;
  const int lane = t & 63, w = t >> 6;
  const int wr = w >> 1, wc = w & 1;
  const int l15 = lane & 15, lhi = lane >> 4;
  const int row0 = blockIdx.x * 128;
  const int n0b  = blockIdx.y;             // 0,1 -> feat; 2,3 -> res

  // staging chunks: 512 chunks of 16B per tile; chunk c: row=c>>2, col8=(c&3)*8
  const int c0 = w * 128 + lane;
  const int c1 = c0 + 64;
  const unsigned short* gA0 = A  + (size_t)(row0 + (c0 >> 2)) * K + (c0 & 3) * 8;
  const unsigned short* gA1 = A  + (size_t)(row0 + (c1 >> 2)) * K + (c1 & 3) * 8;
  const unsigned short* gB0 = BT + (size_t)(n0b * 128 + (c0 >> 2)) * K + (c0 & 3) * 8;
  const unsigned short* gB1 = BT + (size_t)(n0b * 128 + (c1 >> 2)) * K + (c1 & 3) * 8;
  unsigned short* lA0 = &As[w * 1024];
  unsigned short* lA1 = &As[w * 1024 + 512];
  unsigned short* lB0 = &Bs[w * 1024];
  unsigned short* lB1 = &Bs[w * 1024 + 512];

  f32x4 acc[4][4];
  #pragma unroll
  for (int i = 0; i < 4; ++i)
    #pragma unroll
    for (int j = 0; j < 4; ++j)
      acc[i][j] = (f32x4){0.f, 0.f, 0.f, 0.f};

  for (int k0 = 0; k0 < K; k0 += 32) {
    __syncthreads();                       // prev iter's ds_reads done
    gload_lds16(gA0 + k0, lA0);
    gload_lds16(gA1 + k0, lA1);
    gload_lds16(gB0 + k0, lB0);
    gload_lds16(gB1 + k0, lB1);
    __syncthreads();                       // drains vmcnt -> LDS tiles ready

    short8 a[4], b[4];
    #pragma unroll
    for (int im = 0; im < 4; ++im)
      a[im] = *(const short8*)&As[(wr * 64 + im * 16 + l15) * 32 + lhi * 8];
    #pragma unroll
    for (int jn = 0; jn < 4; ++jn)
      b[jn] = *(const short8*)&Bs[(wc * 64 + jn * 16 + l15) * 32 + lhi * 8];
    #pragma unroll
    for (int im = 0; im < 4; ++im)
      #pragma unroll
      for (int jn = 0; jn < 4; ++jn)
        acc[im][jn] = __builtin_amdgcn_mfma_f32_16x16x32_bf16(
            a[im], b[jn], acc[im][jn], 0, 0, 0);
  }

  // C/D layout: col = lane&15, row = (lane>>4)*4 + q   [m89/m91 verified]
  unsigned short* outp = (n0b < 2) ? featbf : resbf;
  const int colbase = (n0b & 1) * 128 + wc * 64;
  #pragma unroll
  for (int im = 0; im < 4; ++im) {
    const int rowb = row0 + wr * 64 + im * 16 + lhi * 4;
    #pragma unroll
    for (int q = 0; q < 4; ++q) {
      if (rowb + q < M) {
        unsigned short* rp = outp + (size_t)(rowb + q) * HF + colbase;
        #pragma unroll
        for (int jn = 0; jn < 4; ++jn)
          rp[jn * 16 + l15] = f2bf(acc[im][jn][q]);
      }
    }
  }

  // el/er for the feat half: wave (n0b,wc) owns head hd's full 64 columns.
  if (n0b < 2) {
    const int hd = n0b * 2 + wc;
    float alv[4], arv[4];
    #pragma unroll
    for (int jn = 0; jn < 4; ++jn) {
      alv[jn] = al[hd * FD + jn * 16 + l15];
      arv[jn] = ar[hd * FD + jn * 16 + l15];
    }
    #pragma unroll
    for (int im = 0; im < 4; ++im) {
      #pragma unroll
      for (int q = 0; q < 4; ++q) {
        float es = 0.f, rs = 0.f;
        #pragma unroll
        for (int jn = 0; jn < 4; ++jn) {
          es = fmaf(acc[im][jn][q], alv[jn], es);
          rs = fmaf(acc[im][jn][q], arv[jn], rs);
        }
        #pragma unroll
        for (int off = 1; off < 16; off <<= 1) {   // reduce across l15 group
          es += __shfl_xor(es, off);
          rs += __shfl_xor(rs, off);
        }
        const int row = row0 + wr * 64 + im * 16 + lhi * 4 + q;
        if (l15 == 0 && row < M) {
          el[row * HEADS + hd] = es;
          er[row * HEADS + hd] = rs;
        }
      }
    }
  }
}

// ---------------------------------------------------------------------------
// Fused conversions + goffs build + HISTOGRAM (counts/cursor pre-zeroed by a
// hipMemsetAsync enqueued before this kernel, so the atomic segment needs no
// intra-kernel ordering): x->bf16 | BT1 | BT2 | goffs | hist(dst).
// goffs[g] = first node index with gid >= g (gid is SORTED).
// ---------------------------------------------------------------------------
__global__ void k_cvt_init(
    const float* __restrict__ x,
    const float* __restrict__ W1, const float* __restrict__ Wres1,
    const float* __restrict__ W2, const float* __restrict__ Wres2,
    unsigned short* __restrict__ xbf, unsigned short* __restrict__ BT1,
    unsigned short* __restrict__ BT2, const int* __restrict__ gid,
    int* __restrict__ goffs, const int* __restrict__ dst,
    int* __restrict__ counts, int n4, int N, int G, int E)
{
  int i = blockIdx.x * 256 + threadIdx.x;
  if (i < n4) {
    float4 v = ((const float4*)x)[i];
    ushort4 o;
    o.x = f2bf(v.x); o.y = f2bf(v.y); o.z = f2bf(v.z); o.w = f2bf(v.w);
    ((ushort4*)xbf)[i] = o;
    return;
  }
  i -= n4;
  if (i < 512 * 64) {
    int j = i >> 6, k = i & 63;
    float v = (j < HF) ? W1[k * HF + j] : Wres1[k * HF + (j - HF)];
    BT1[i] = f2bf(v);
    return;
  }
  i -= 512 * 64;
  if (i < 512 * 256) {
    int j = i >> 8, k = i & 255;
    float v = (j < HF) ? W2[k * HF + j] : Wres2[k * HF + (j - HF)];
    BT2[i] = f2bf(v);
    return;
  }
  i -= 512 * 256;
  if (i < N) {
    const int g1 = gid[i];
    if (i == 0) {
      for (int g = 0; g <= g1; ++g) goffs[g] = 0;
    } else {
      const int g0 = gid[i - 1];
      for (int g = g0 + 1; g <= g1; ++g) goffs[g] = i;
    }
    if (i == N - 1) {
      for (int g = g1 + 1; g <= G; ++g) goffs[g] = N;
    }
    return;
  }
  i -= N;
  if (i < E) atomicAdd(&counts[dst[i]], 1);   // histogram (counts memset'd)
}

// ---------------------------------------------------------------------------
// CSR build: scan1 (per-1024 block scan, raw offs) -> scan2 (bsum exclusive
// scan). NO scan3: consumers apply fin(i) = offs[i] + bsum[i>>10] inline.
// ---------------------------------------------------------------------------
__global__ __launch_bounds__(256) void k_scan1(
    const int* __restrict__ counts, int* __restrict__ offs,
    int* __restrict__ bsum, int n)
{
  __shared__ int lds[256];
  const int b = blockIdx.x, t = threadIdx.x;
  const int base = b * 1024 + t * 4;
  int v[4];
  #pragma unroll
  for (int i = 0; i < 4; ++i) { int idx = base + i; v[i] = (idx < n) ? counts[idx] : 0; }
  int tsum = v[0] + v[1] + v[2] + v[3];
  lds[t] = tsum;
  __syncthreads();
  for (int off = 1; off < 256; off <<= 1) {
    int x = (t >= off) ? lds[t - off] : 0;
    __syncthreads();
    lds[t] += x;
    __syncthreads();
  }
  int run = lds[t] - tsum;
  #pragma unroll
  for (int i = 0; i < 4; ++i) {
    int idx = base + i;
    if (idx < n) offs[idx] = run;
    run += v[i];
  }
  if (t == 255) bsum[b] = lds[255];
}

// Wave-parallel block-sum exclusive scan (nb <= 64 here; serial fallback).
__global__ void k_scan2(int* __restrict__ bsum, int nb) {
  const int t = threadIdx.x;                  // 64 threads
  if (nb <= 64) {
    int v = (t < nb) ? bsum[t] : 0;
    int inc = v;
    #pragma unroll
    for (int off = 1; off < 64; off <<= 1) {
      int u = __shfl_up(inc, off);
      if (t >= off) inc += u;
    }
    if (t < nb) bsum[t] = inc - v;            // exclusive prefix
  } else if (t == 0) {
    int run = 0;
    for (int b = 0; b < nb; ++b) { int x = bsum[b]; bsum[b] = run; run += x; }
  }
}

__global__ void k_scatter(const int* __restrict__ src, const int* __restrict__ dst,
                          const int* __restrict__ offs, const int* __restrict__ bsum,
                          int* __restrict__ cursor, int* __restrict__ csr_src, int E) {
  int i = blockIdx.x * 256 + threadIdx.x;
  if (i < E) {
    int d = dst[i];
    int pos = offs[d] + bsum[d >> 10] + atomicAdd(&cursor[d], 1);
    csr_src[pos] = src[i];
  }
}

// ---------------------------------------------------------------------------
// GAT aggregation layer 1 (round-14 core, one barrier; round-17 wave-owned
// pass-1 layout). offs is raw; fin(i) = offs[i] + bsum[i>>10]; fin(N) = E.
//   Pass 1: wave w scores edges j == w (mod 4) (lane = 4*e + h), exp-weights
//   -> sw4[j][h] (same-wave producer/consumer, no mid barrier); per-head
//   denom partials -> sden[w][h]. No max-subtraction (scores O(+-3)).
//   Pass 2: wave w gathers its edges; lane loads ushort4 (its 4 features of
//   the 512 B row, head = lane>>4); weight = LDS broadcast; f32 accumulate.
//   Epilogue (wave 0): sum 4 waves, /denom, +res, +bias, ELU -> bf16 h1 row.
// ---------------------------------------------------------------------------
#define DCAP 128
__global__ __launch_bounds__(256) void agg_l1(
    const unsigned short* __restrict__ feat, const unsigned short* __restrict__ res,
    const float* __restrict__ el, const float* __restrict__ er,
    const float* __restrict__ bias, const int* __restrict__ csr_src,
    const int* __restrict__ offs, const int* __restrict__ bsum,
    unsigned short* __restrict__ outbf, int N, int E)
{
  __shared__ int    ssrc[DCAP];
  __shared__ float  sw4[DCAP * 4];          // [j][h]
  __shared__ float  sden[4][4];             // [wave][h]
  __shared__ float4 sacc[4][64];            // [wave][lane]
  const int n = blockIdx.x;
  const int t = threadIdx.x;
  const int lane = t & 63, w = t >> 6;
  const int h = lane & 3, e0 = lane >> 2;   // pass-1 layout (wave-owned j)
  const int hd = lane >> 4;                 // pass-2 head
  const int s0  = offs[n] + bsum[n >> 10];
  const int se  = (n + 1 < N) ? offs[n + 1] + bsum[(n + 1) >> 10] : E;
  const int deg = se - s0;                  // >= 1 (self-loops)
  const bool cached = (deg <= DCAP);

  if (cached) {
    const float ernh = er[n * HEADS + h];
    float dp = 0.f;
    for (int j = w + 4 * e0; j < deg; j += 64) {
      int s = csr_src[s0 + j];
      float sc = el[s * HEADS + h] + ernh;
      sc = sc > 0.f ? sc : NEG_SLOPE * sc;  // leaky_relu
      float wv = __expf(sc);
      sw4[j * 4 + h] = wv;
      if (h == 0) ssrc[j] = s;
      dp += wv;
    }
    #pragma unroll
    for (int off = 4; off < 64; off <<= 1) dp += __shfl_xor(dp, off);
    if (lane < 4) sden[w][lane] = dp;
  }
  // NO mid barrier: wave w reads only its own sw4/ssrc writes below.

  float4 acc = make_float4(0.f, 0.f, 0.f, 0.f);
  if (cached) {
    int j = w;
    for (; j + 4 < deg; j += 8) {           // 2-way unroll
      int   sa = ssrc[j],         sb = ssrc[j + 4];
      float wa = sw4[j * 4 + hd], wb = sw4[(j + 4) * 4 + hd];
      ushort4 fa = *((const ushort4*)&feat[(size_t)sa * HF] + lane);
      ushort4 fb = *((const ushort4*)&feat[(size_t)sb * HF] + lane);
      acc.x = fmaf(wa, bf2f(fa.x), acc.x); acc.x = fmaf(wb, bf2f(fb.x), acc.x);
      acc.y = fmaf(wa, bf2f(fa.y), acc.y); acc.y = fmaf(wb, bf2f(fb.y), acc.y);
      acc.z = fmaf(wa, bf2f(fa.z), acc.z); acc.z = fmaf(wb, bf2f(fb.z), acc.z);
      acc.w = fmaf(wa, bf2f(fa.w), acc.w); acc.w = fmaf(wb, bf2f(fb.w), acc.w);
    }
    if (j < deg) {
      int   sa = ssrc[j];
      float wa = sw4[j * 4 + hd];
      ushort4 fa = *((const ushort4*)&feat[(size_t)sa * HF] + lane);
      acc.x = fmaf(wa, bf2f(fa.x), acc.x);
      acc.y = fmaf(wa, bf2f(fa.y), acc.y);
      acc.z = fmaf(wa, bf2f(fa.z), acc.z);
      acc.w = fmaf(wa, bf2f(fa.w), acc.w);
    }
  } else {                                  // rare deg>128 fallback
    const float ernd = er[n * HEADS + hd];
    float dpu = 0.f;
    for (int j = w; j < deg; j += 4) {
      int s = csr_src[s0 + j];
      float sc = el[s * HEADS + hd] + ernd;
      sc = sc > 0.f ? sc : NEG_SLOPE * sc;
      float wv = __expf(sc);
      dpu += wv;
      ushort4 fa = *((const ushort4*)&feat[(size_t)s * HF] + lane);
      acc.x = fmaf(wv, bf2f(fa.x), acc.x);
      acc.y = fmaf(wv, bf2f(fa.y), acc.y);
      acc.z = fmaf(wv, bf2f(fa.z), acc.z);
      acc.w = fmaf(wv, bf2f(fa.w), acc.w);
    }
    if ((lane & 15) == 0) sden[w][hd] = dpu;
  }
  sacc[w][lane] = acc;
  __syncthreads();

  if (w == 0) {
    float4 a0 = sacc[0][lane], a1 = sacc[1][lane],
           a2 = sacc[2][lane], a3 = sacc[3][lane];
    float denom = sden[0][hd] + sden[1][hd] + sden[2][hd] + sden[3][hd];
    float rden = 1.f / denom;
    ushort4 rv = *((const ushort4*)&res[(size_t)n * HF] + lane);
    float4  bv = *((const float4*)bias + lane);
    float v0 = (a0.x + a1.x + a2.x + a3.x) * rden + bf2f(rv.x) + bv.x;
    float v1 = (a0.y + a1.y + a2.y + a3.y) * rden + bf2f(rv.y) + bv.y;
    float v2 = (a0.z + a1.z + a2.z + a3.z) * rden + bf2f(rv.z) + bv.z;
    float v3 = (a0.w + a1.w + a2.w + a3.w) * rden + bf2f(rv.w) + bv.w;
    v0 = v0 > 0.f ? v0 : expm1f(v0);        // ELU(alpha=1)
    v1 = v1 > 0.f ? v1 : expm1f(v1);
    v2 = v2 > 0.f ? v2 : expm1f(v2);
    v3 = v3 > 0.f ? v3 : expm1f(v3);
    ushort4 o;
    o.x = f2bf(v0); o.y = f2bf(v1); o.z = f2bf(v2); o.w = f2bf(v3);
    *((ushort4*)&outbf[(size_t)n * HF] + lane) = o;
  }
}

// ---------------------------------------------------------------------------
// GAT aggregation layer 2 — same one-barrier core; epilogue writes the f32
// h2 row + node_w[n] = sigmoid(dot(h2row, Ww)+bw). No atomics (gid sorted;
// per-graph reduction in k_rp).
// ---------------------------------------------------------------------------
__global__ __launch_bounds__(256) void agg_l2(
    const unsigned short* __restrict__ feat, const unsigned short* __restrict__ res,
    const float* __restrict__ el, const float* __restrict__ er,
    const float* __restrict__ bias, const int* __restrict__ csr_src,
    const int* __restrict__ offs, const int* __restrict__ bsum,
    const float* __restrict__ Ww, const float* __restrict__ bw,
    float* __restrict__ h2out, float* __restrict__ node_w, int N, int E)
{
  __shared__ int    ssrc[DCAP];
  __shared__ float  sw4[DCAP * 4];
  __shared__ float  sden[4][4];
  __shared__ float4 sacc[4][64];
  const int n = blockIdx.x;
  const int t = threadIdx.x;
  const int lane = t & 63, w = t >> 6;
  const int h = lane & 3, e0 = lane >> 2;   // pass-1 layout (wave-owned j)
  const int hd = lane >> 4;
  const int s0  = offs[n] + bsum[n >> 10];
  const int se  = (n + 1 < N) ? offs[n + 1] + bsum[(n + 1) >> 10] : E;
  const int deg = se - s0;
  const bool cached = (deg <= DCAP);

  if (cached) {
    const float ernh = er[n * HEADS + h];
    float dp = 0.f;
    for (int j = w + 4 * e0; j < deg; j += 64) {
      int s = csr_src[s0 + j];
      float sc = el[s * HEADS + h] + ernh;
      sc = sc > 0.f ? sc : NEG_SLOPE * sc;
      float wv = __expf(sc);
      sw4[j * 4 + h] = wv;
      if (h == 0) ssrc[j] = s;
      dp += wv;
    }
    #pragma unroll
    for (int off = 4; off < 64; off <<= 1) dp += __shfl_xor(dp, off);
    if (lane < 4) sden[w][lane] = dp;
  }
  // NO mid barrier (same-wave LDS producer/consumer).

  float4 acc = make_float4(0.f, 0.f, 0.f, 0.f);
  if (cached) {
    int j = w;
    for (; j + 4 < deg; j += 8) {
      int   sa = ssrc[j],         sb = ssrc[j + 4];
      float wa = sw4[j * 4 + hd], wb = sw4[(j + 4) * 4 + hd];
      ushort4 fa = *((const ushort4*)&feat[(size_t)sa * HF] + lane);
      ushort4 fb = *((const ushort4*)&feat[(size_t)sb * HF] + lane);
      acc.x = fmaf(wa, bf2f(fa.x), acc.x); acc.x = fmaf(wb, bf2f(fb.x), acc.x);
      acc.y = fmaf(wa, bf2f(fa.y), acc.y); acc.y = fmaf(wb, bf2f(fb.y), acc.y);
      acc.z = fmaf(wa, bf2f(fa.z), acc.z); acc.z = fmaf(wb, bf2f(fb.z), acc.z);
      acc.w = fmaf(wa, bf2f(fa.w), acc.w); acc.w = fmaf(wb, bf2f(fb.w), acc.w);
    }
    if (j < deg) {
      int   sa = ssrc[j];
      float wa = sw4[j * 4 + hd];
      ushort4 fa = *((const ushort4*)&feat[(size_t)sa * HF] + lane);
      acc.x = fmaf(wa, bf2f(fa.x), acc.x);
      acc.y = fmaf(wa, bf2f(fa.y), acc.y);
      acc.z = fmaf(wa, bf2f(fa.z), acc.z);
      acc.w = fmaf(wa, bf2f(fa.w), acc.w);
    }
  } else {
    const float ernd = er[n * HEADS + hd];
    float dpu = 0.f;
    for (int j = w; j < deg; j += 4) {
      int s = csr_src[s0 + j];
      float sc = el[s * HEADS + hd] + ernd;
      sc = sc > 0.f ? sc : NEG_SLOPE * sc;
      float wv = __expf(sc);
      dpu += wv;
      ushort4 fa = *((const ushort4*)&feat[(size_t)s * HF] + lane);
      acc.x = fmaf(wv, bf2f(fa.x), acc.x);
      acc.y = fmaf(wv, bf2f(fa.y), acc.y);
      acc.z = fmaf(wv, bf2f(fa.z), acc.z);
      acc.w = fmaf(wv, bf2f(fa.w), acc.w);
    }
    if ((lane & 15) == 0) sden[w][hd] = dpu;
  }
  sacc[w][lane] = acc;
  __syncthreads();

  if (w == 0) {
    float4 a0 = sacc[0][lane], a1 = sacc[1][lane],
           a2 = sacc[2][lane], a3 = sacc[3][lane];
    float denom = sden[0][hd] + sden[1][hd] + sden[2][hd] + sden[3][hd];
    float rden = 1.f / denom;
    ushort4 rv = *((const ushort4*)&res[(size_t)n * HF] + lane);
    float4  bv = *((const float4*)bias + lane);
    float v0 = (a0.x + a1.x + a2.x + a3.x) * rden + bf2f(rv.x) + bv.x;
    float v1 = (a0.y + a1.y + a2.y + a3.y) * rden + bf2f(rv.y) + bv.y;
    float v2 = (a0.z + a1.z + a2.z + a3.z) * rden + bf2f(rv.z) + bv.z;
    float v3 = (a0.w + a1.w + a2.w + a3.w) * rden + bf2f(rv.w) + bv.w;
    v0 = v0 > 0.f ? v0 : expm1f(v0);        // ELU(alpha=1)
    v1 = v1 > 0.f ? v1 : expm1f(v1);
    v2 = v2 > 0.f ? v2 : expm1f(v2);
    v3 = v3 > 0.f ? v3 : expm1f(v3);
    #pragma unroll
    for (int off = 16; off < 64; off <<= 1) {     // sum across the 4 heads
      v0 += __shfl_xor(v0, off);
      v1 += __shfl_xor(v1, off);
      v2 += __shfl_xor(v2, off);
      v3 += __shfl_xor(v3, off);
    }
    if (lane < 16) {                        // h2 row lives in lanes 0-15
      const float m0 = 0.25f * v0, m1 = 0.25f * v1,
                  m2 = 0.25f * v2, m3 = 0.25f * v3;
      *((float4*)&h2out[(size_t)n * FD] + lane) = make_float4(m0, m1, m2, m3);
      const float4 wwv = ((const float4*)Ww)[lane];
      float part = m0 * wwv.x + m1 * wwv.y + m2 * wwv.z + m3 * wwv.w;
      #pragma unroll
      for (int off = 1; off < 16; off <<= 1)
        part += __shfl_xor(part, off);
      if (lane == 0)
        node_w[n] = 1.f / (1.f + __expf(-(part + bw[0])));
    }
  }
}

// ---------------------------------------------------------------------------
// Fused per-graph readout + predictor: one WAVE per graph (gid sorted ->
// contiguous node range via goffs, zero atomics). Lane f streams wsum/hmax;
// gfeat staged in LDS; lanes 0-31 compute the 32 hidden units; shfl-reduce
// the final dot. Empty graphs: ws=0, mx=-inf (JAX segment semantics).
// ---------------------------------------------------------------------------
__global__ __launch_bounds__(256) void k_rp(
    const float* __restrict__ h2, const float* __restrict__ node_w,
    const int* __restrict__ goffs,
    const float* __restrict__ Wp1, const float* __restrict__ bp1,
    const float* __restrict__ Wp2, const float* __restrict__ bp2,
    float* __restrict__ out, int G)
{
  __shared__ float lws[4][FD];
  __shared__ float lmx[4][FD];
  const int w = threadIdx.x >> 6, lane = threadIdx.x & 63;
  const int g = blockIdx.x * 4 + w;

  float ws = 0.f, mx = -INFINITY;
  if (g < G) {
    const int n0 = goffs[g], n1 = goffs[g + 1];
    for (int n = n0; n < n1; ++n) {
      float v  = h2[(size_t)n * FD + lane];
      float wn = node_w[n];
      ws = fmaf(wn, v, ws);
      mx = fmaxf(mx, v);
    }
  }
  lws[w][lane] = ws;
  lmx[w][lane] = mx;
  __syncthreads();

  float acc = 0.f;
  if (g < G && lane < 32) {
    acc = bp1[lane];
    #pragma unroll 4
    for (int k = 0; k < FD; ++k)
      acc = fmaf(lws[w][k], Wp1[k * 32 + lane], acc);
    #pragma unroll 4
    for (int k = 0; k < FD; ++k)
      acc = fmaf(lmx[w][k], Wp1[(FD + k) * 32 + lane], acc);
    acc = fmaxf(acc, 0.f) * Wp2[lane];
  }
  #pragma unroll
  for (int off = 1; off < 32; off <<= 1)    // reduce lanes 0-31
    acc += __shfl_xor(acc, off);
  if (g < G && lane == 0) out[g] = acc + bp2[0];
}

// ---------------------------------------------------------------------------
extern "C" void kernel_launch(void* const* d_in, const int* in_sizes, int n_in,
                              void* d_out, int out_size, void* d_ws, size_t ws_size,
                              hipStream_t stream) {
  const float* x     = (const float*)d_in[0];
  const int*   src   = (const int*)  d_in[1];
  const int*   dst   = (const int*)  d_in[2];
  const int*   gid   = (const int*)  d_in[3];
  const float* W1    = (const float*)d_in[4];
  const float* al1   = (const float*)d_in[5];
  const float* ar1   = (const float*)d_in[6];
  const float* b1    = (const float*)d_in[7];
  const float* Wres1 = (const float*)d_in[8];
  const float* W2    = (const float*)d_in[9];
  const float* al2   = (const float*)d_in[10];
  const float* ar2   = (const float*)d_in[11];
  const float* b2    = (const float*)d_in[12];
  const float* Wres2 = (const float*)d_in[13];
  const float* Ww    = (const float*)d_in[14];
  const float* bw    = (const float*)d_in[15];
  const float* Wp1   = (const float*)d_in[16];
  const float* bp1   = (const float*)d_in[17];
  const float* Wp2   = (const float*)d_in[18];
  const float* bp2   = (const float*)d_in[19];
  float* out = (float*)d_out;

  const int N = in_sizes[3];        // gid has N elements
  const int E = in_sizes[1];        // src has E elements
  const int G = out_size;           // output is [G,1]
  const int Mpad = (N + 127) & ~127;

  // ---- workspace carve (256B-aligned) ----
  char* p = (char*)d_ws;
  auto alloc = [&](size_t bytes) {
    char* r = p;
    p += (bytes + 255) & ~(size_t)255;
    return r;
  };
  const size_t npad = ((size_t)N * 4 + 255) & ~(size_t)255;
  unsigned short* featbf  = (unsigned short*)alloc((size_t)Mpad * HF * 2);
  unsigned short* resbf   = (unsigned short*)alloc((size_t)Mpad * HF * 2);
  float*          el      = (float*)         alloc((size_t)N * HEADS * 4);
  float*          er      = (float*)         alloc((size_t)N * HEADS * 4);
  int*            counts  = (int*)           alloc(npad * 2);  // counts|cursor
  int*            cursor  = (int*)((char*)counts + npad);
  int*            offs    = (int*)           alloc((size_t)N * 4);
  const int nb            = (N + 1023) / 1024;
  int*            bsum    = (int*)           alloc((size_t)nb * 4);
  int*            csr_src = (int*)           alloc((size_t)E * 4);
  float*          h2      = (float*)         alloc((size_t)N * FD * 4);
  float*          node_w  = (float*)         alloc((size_t)N * 4);
  int*            goffs   = (int*)           alloc((size_t)(G + 1) * 4);
  unsigned short* xbf     = (unsigned short*)alloc((size_t)Mpad * 64 * 2);
  unsigned short* h1bf    = (unsigned short*)alloc((size_t)Mpad * HF * 2);
  unsigned short* BT1     = (unsigned short*)alloc((size_t)512 * 64 * 2);
  unsigned short* BT2     = (unsigned short*)alloc((size_t)512 * 256 * 2);
  (void)ws_size; (void)n_in;

  // ---- counts+cursor zero (one memset), then fused cvt/goffs/hist ----
  hipMemsetAsync(counts, 0, npad * 2, stream);
  const int n4 = N * 64 / 4;
  const int init_total = n4 + 512 * 64 + 512 * 256 + N + E;
  k_cvt_init<<<(init_total + 255) / 256, 256, 0, stream>>>(
      x, W1, Wres1, W2, Wres2, xbf, BT1, BT2,
      gid, goffs, dst, counts, n4, N, G, E);

  // ---- CSR by destination (raw offs + bsum; consumers finalize inline) ----
  k_scan1  <<<nb, 256, 0, stream>>>(counts, offs, bsum, N);
  k_scan2  <<<1, 64, 0, stream>>>(bsum, nb);
  k_scatter<<<(E + 255) / 256, 256, 0, stream>>>(src, dst, offs, bsum,
                                                 cursor, csr_src, E);

  // Row-tile fastest (round-14 proven ordering).
  dim3 gg(Mpad / 128, 4);

  // ---- layer 1 (flatten) ----
  gemm_mfma<64> <<<gg, 256, 0, stream>>>(xbf, BT1, al1, ar1,
                                         featbf, resbf, el, er, N);
  agg_l1        <<<N, 256, 0, stream>>>(featbf, resbf, el, er, b1, csr_src,
                                        offs, bsum, h1bf, N, E);

  // ---- layer 2 (mean) ----
  gemm_mfma<256><<<gg, 256, 0, stream>>>(h1bf, BT2, al2, ar2,
                                         featbf, resbf, el, er, N);
  agg_l2        <<<N, 256, 0, stream>>>(featbf, resbf, el, er, b2, csr_src,
                                        offs, bsum, Ww, bw, h2, node_w, N, E);

  // ---- fused per-graph readout + predictor (no atomics) ----
  k_rp<<<(G + 3) / 4, 256, 0, stream>>>(h2, node_w, goffs,
                                        Wp1, bp1, Wp2, bp2, out, G);
}